// Round 5
// baseline (3349.713 us; speedup 1.0000x reference)
//
#include <hip/hip_runtime.h>
#include <cstdint>
#include <cstddef>

// Problem constants
#define BB   4
#define TT   1024
#define CC   1024
#define HH   16
#define HSS  64
#define NNtok 4096            // B*T
#define EPSGN 0.00064f

typedef unsigned short bf16u;
#define SLOT 4194304ull       // elements per 8MiB bf16 slot (= NNtok*CC)

__device__ __forceinline__ float bf2f(bf16u u){
  union { unsigned int i; float f; } cv; cv.i = ((unsigned int)u) << 16; return cv.f;
}
__device__ __forceinline__ bf16u f2bf(float f){
  union { float f; unsigned int i; } cv; cv.f = f;
  unsigned int x = cv.i;
  return (bf16u)((x + 0x7fffu + ((x >> 16) & 1u)) >> 16);   // RNE
}
__device__ __forceinline__ void ld4bf(const bf16u* p, float* o){
  ushort4 u = *reinterpret_cast<const ushort4*>(p);
  o[0]=bf2f(u.x); o[1]=bf2f(u.y); o[2]=bf2f(u.z); o[3]=bf2f(u.w);
}
__device__ __forceinline__ void st4bf(bf16u* p, const float* v){
  ushort4 u; u.x=f2bf(v[0]); u.y=f2bf(v[1]); u.z=f2bf(v[2]); u.w=f2bf(v[3]);
  *reinterpret_cast<ushort4*>(p) = u;
}
__device__ __forceinline__ void ld4f(const float* p, float* o){
  float4 v = *reinterpret_cast<const float4*>(p);
  o[0]=v.x; o[1]=v.y; o[2]=v.z; o[3]=v.w;
}
__device__ __forceinline__ float sigm(float x){ return 1.f / (1.f + expf(-x)); }
__device__ __forceinline__ float red16(float v){
  v += __shfl_xor(v, 1, 16); v += __shfl_xor(v, 2, 16);
  v += __shfl_xor(v, 4, 16); v += __shfl_xor(v, 8, 16);
  return v;
}

// ---------------------------------------------------------------------------
// mix = x + (x[t-1]-x[t])*time_maa_x  (x[-1]=0), stored bf16
// ---------------------------------------------------------------------------
__global__ __launch_bounds__(256) void k_prep(const float* __restrict__ x,
                                              const float* __restrict__ tmx,
                                              bf16u* __restrict__ MIX){
  int e = (blockIdx.x * 256 + threadIdx.x) * 4;
  int n = e >> 10;
  int c = e & (CC - 1);
  int t = n & (TT - 1);
  float xf[4]; ld4f(x + e, xf);
  float pf[4] = {0.f, 0.f, 0.f, 0.f};
  if (t > 0) ld4f(x + e - CC, pf);
  float tm[4]; ld4f(tmx + c, tm);
  float mv[4];
  #pragma unroll
  for (int i = 0; i < 4; ++i) mv[i] = xf[i] + (pf[i] - xf[i]) * tm[i];
  st4bf(MIX + e, mv);
}

// ---------------------------------------------------------------------------
// Tiled NT GEMM: OUT[M,N] = X[M,K] * W[N,K]^T ; X = ws bf16, W = f32 input.
// ACT: 0 none, 1 tanh. OB: 1 -> bf16 out, 0 -> f32 out.
// ---------------------------------------------------------------------------
template<int BM, int BN, int BK, int TM, int TN, int ACT, bool OB>
__global__ __launch_bounds__(256) void k_gemm_nt(const bf16u* __restrict__ X,
                                                 const float* __restrict__ W,
                                                 void* __restrict__ OUTv,
                                                 int Nd, int Kd){
  __shared__ float Xs[BK][BM + 1];
  __shared__ float Ws[BK][BN + 1];
  const int tid  = threadIdx.x;
  const int bm0  = blockIdx.y * BM;
  const int bn0  = blockIdx.x * BN;
  const int tidn = tid % (BN / TN);
  const int tidm = tid / (BN / TN);

  float acc[TM][TN];
  #pragma unroll
  for (int i = 0; i < TM; ++i)
    #pragma unroll
    for (int j = 0; j < TN; ++j) acc[i][j] = 0.f;

  for (int k0 = 0; k0 < Kd; k0 += BK){
    for (int i = tid; i < BM * BK; i += 256){
      int m = i / BK, kk = i % BK;
      Xs[kk][m] = bf2f(X[(size_t)(bm0 + m) * Kd + k0 + kk]);
    }
    for (int i = tid; i < BN * BK; i += 256){
      int nn = i / BK, kk = i % BK;
      Ws[kk][nn] = W[(size_t)(bn0 + nn) * Kd + k0 + kk];
    }
    __syncthreads();
    #pragma unroll
    for (int kk = 0; kk < BK; ++kk){
      float rm[TM], rn[TN];
      #pragma unroll
      for (int i = 0; i < TM; ++i) rm[i] = Xs[kk][tidm * TM + i];
      #pragma unroll
      for (int j = 0; j < TN; ++j) rn[j] = Ws[kk][tidn * TN + j];
      #pragma unroll
      for (int i = 0; i < TM; ++i)
        #pragma unroll
        for (int j = 0; j < TN; ++j) acc[i][j] += rm[i] * rn[j];
    }
    __syncthreads();
  }

  #pragma unroll
  for (int i = 0; i < TM; ++i){
    int row = bm0 + tidm * TM + i;
    #pragma unroll
    for (int j = 0; j < TN; ++j){
      int col = bn0 + tidn * TN + j;
      float v = acc[i][j];
      if (ACT == 1) v = tanhf(v);
      if (OB) ((bf16u*)OUTv)[(size_t)row * Nd + col] = f2bf(v);
      else    ((float*)OUTv)[(size_t)row * Nd + col] = v;
    }
  }
}

// ---------------------------------------------------------------------------
// xm[g] = x + xx*(lo_g @ maa_w2[g] + time_maa[g]), xx recomputed from x
// ---------------------------------------------------------------------------
__global__ __launch_bounds__(256) void k_xm(const float* __restrict__ x,
                                            const float* __restrict__ LO,
                                            const float* __restrict__ tmaa,
                                            const float* __restrict__ mw2,
                                            bf16u* __restrict__ X0, bf16u* __restrict__ X1,
                                            bf16u* __restrict__ X2, bf16u* __restrict__ X3){
  int n = blockIdx.x, tid = threadIdx.x;
  __shared__ float lo_l[128];
  if (tid < 128) lo_l[tid] = LO[(size_t)n * 128 + tid];
  __syncthreads();
  int c = tid * 4;
  int t = n & (TT - 1);
  size_t e = (size_t)n * CC + c;
  float xf[4]; ld4f(x + e, xf);
  float pf[4] = {0.f, 0.f, 0.f, 0.f};
  if (t > 0) ld4f(x + e - CC, pf);
  float xxa[4];
  #pragma unroll
  for (int i = 0; i < 4; ++i) xxa[i] = pf[i] - xf[i];

  bf16u* outs[4] = {X0, X1, X2, X3};
  #pragma unroll
  for (int g = 0; g < 4; ++g){
    float a[4]; ld4f(tmaa + (size_t)g * CC + c, a);
    #pragma unroll 8
    for (int j = 0; j < 32; ++j){
      float l = lo_l[g * 32 + j];
      float wv[4]; ld4f(mw2 + (size_t)(g * 32 + j) * CC + c, wv);
      a[0] += l * wv[0]; a[1] += l * wv[1]; a[2] += l * wv[2]; a[3] += l * wv[3];
    }
    float r[4];
    #pragma unroll
    for (int i = 0; i < 4; ++i) r[i] = xf[i] + xxa[i] * a[i];
    st4bf(outs[g] + e, r);
  }
}

// ---------------------------------------------------------------------------
// Fused elementwise + small LoRA second matmuls.
// KF (final k, bf16, in-place over K0), KKN (bf16), Bb (-kk*a, bf16),
// UX = exp(w) (bf16; k_rec computes wt = exp(-UX) in f32)
// ---------------------------------------------------------------------------
__global__ __launch_bounds__(256) void k_elem(bf16u* __restrict__ K0,
    const float* __restrict__ DT, const float* __restrict__ KT,
    const float* __restrict__ AT, const float* __restrict__ MAT,
    const float* __restrict__ MKT,
    const float* __restrict__ dw2, const float* __restrict__ kw2,
    const float* __restrict__ aw2, const float* __restrict__ maw2,
    const float* __restrict__ mkw2,
    const float* __restrict__ td,  const float* __restrict__ taa,
    const float* __restrict__ tma, const float* __restrict__ tmk,
    bf16u* __restrict__ KKN, bf16u* __restrict__ Bb, bf16u* __restrict__ UX){
  int n = blockIdx.x, tid = threadIdx.x;
  __shared__ float dt_l[64], kt_l[16], at_l[16], mat_l[16], mkt_l[16];
  if (tid < 64)        dt_l[tid]       = DT[(size_t)n * 64 + tid];
  else if (tid < 80)   kt_l[tid - 64]  = KT[(size_t)n * 16 + tid - 64];
  else if (tid < 96)   at_l[tid - 80]  = AT[(size_t)n * 16 + tid - 80];
  else if (tid < 112)  mat_l[tid - 96] = MAT[(size_t)n * 16 + tid - 96];
  else if (tid < 128)  mkt_l[tid - 112]= MKT[(size_t)n * 16 + tid - 112];
  __syncthreads();
  int c = tid * 4;
  size_t e = (size_t)n * CC + c;

  float w2a[4] = {0,0,0,0};
  #pragma unroll 8
  for (int j = 0; j < 64; ++j){
    float d = dt_l[j];
    float wv[4]; ld4f(dw2 + (size_t)j * CC + c, wv);
    w2a[0] += d*wv[0]; w2a[1] += d*wv[1]; w2a[2] += d*wv[2]; w2a[3] += d*wv[3];
  }
  float kkk4[4] = {0,0,0,0}, aa4[4] = {0,0,0,0}, mam4[4] = {0,0,0,0}, mkm4[4] = {0,0,0,0};
  #pragma unroll
  for (int j = 0; j < 16; ++j){
    float wv[4];
    float s;
    s = kt_l[j];  ld4f(kw2  + (size_t)j * CC + c, wv);
    kkk4[0]+=s*wv[0]; kkk4[1]+=s*wv[1]; kkk4[2]+=s*wv[2]; kkk4[3]+=s*wv[3];
    s = at_l[j];  ld4f(aw2  + (size_t)j * CC + c, wv);
    aa4[0]+=s*wv[0];  aa4[1]+=s*wv[1];  aa4[2]+=s*wv[2];  aa4[3]+=s*wv[3];
    s = mat_l[j]; ld4f(maw2 + (size_t)j * CC + c, wv);
    mam4[0]+=s*wv[0]; mam4[1]+=s*wv[1]; mam4[2]+=s*wv[2]; mam4[3]+=s*wv[3];
    s = mkt_l[j]; ld4f(mkw2 + (size_t)j * CC + c, wv);
    mkm4[0]+=s*wv[0]; mkm4[1]+=s*wv[1]; mkm4[2]+=s*wv[2]; mkm4[3]+=s*wv[3];
  }

  float k0a[4]; ld4bf(K0 + e, k0a);
  float td4[4], taa4[4], tma4[4], tmk4[4];
  ld4f(td + c, td4); ld4f(taa + c, taa4);
  ld4f(tma + c, tma4); ld4f(tmk + c, tmk4);

  float kkv[4];
  float ssq = 0.f;
  #pragma unroll
  for (int i = 0; i < 4; ++i){ kkv[i] = k0a[i] + kkk4[i]; ssq += kkv[i]*kkv[i]; }
  ssq = red16(ssq);
  float rinv = 1.f / fmaxf(sqrtf(ssq), 1e-12f);

  float kkn[4], outb[4], outkf[4], outu[4];
  #pragma unroll
  for (int i = 0; i < 4; ++i){
    float z  = td4[i] + w2a[i];
    float nz = -z;
    float sp = (nz > 15.f) ? nz : log1pf(expf(nz));
    float w  = -sp - 0.5f;               // <= -0.5
    float av = sigm(taa4[i] + aa4[i]);
    float mav = sigm(tma4[i] + mam4[i]);
    float mkv = sigm(tmk4[i] + mkm4[i]);
    kkn[i]  = kkv[i] * rinv;
    outb[i] = -kkn[i] * av;
    outkf[i]= k0a[i] * (mav + av * (1.f - mav)) * expf(w * mkv);
    outu[i] = expf(w);                   // in (0, 0.61]
  }
  st4bf(KKN + e, kkn);
  st4bf(Bb  + e, outb);
  st4bf(K0  + e, outkf);   // in-place: K0 -> KF
  st4bf(UX  + e, outu);
}

// ---------------------------------------------------------------------------
// Recurrence: one block per (b,h). thread (i = tid>>2, jg = tid&3) owns
// S[i][jg*16 .. jg*16+15]. Y written bf16.
// ---------------------------------------------------------------------------
__global__ __launch_bounds__(256) void k_rec(const bf16u* __restrict__ Q,
                                             const bf16u* __restrict__ UX,
                                             const bf16u* __restrict__ KFt,
                                             const bf16u* __restrict__ Vt,
                                             const bf16u* __restrict__ Aa,
                                             const bf16u* __restrict__ Bv,
                                             bf16u* __restrict__ Y){
  int bh = blockIdx.x;
  int b = bh >> 4, h = bh & 15;
  int tid = threadIdx.x;
  int i  = tid >> 2, jg = tid & 3, j0 = jg * 16;
  int cc = tid & 63, sel = tid >> 6;
  __shared__ float buf[6 * 64];
  float S[16];
  #pragma unroll
  for (int u = 0; u < 16; ++u) S[u] = 0.f;
  size_t base = (size_t)(b * TT) * CC + h * HSS;

  for (int t = 0; t < TT; ++t, base += CC){
    __syncthreads();   // previous step's reads done before restaging
    if (sel == 0){
      buf[cc]       = bf2f(Q[base + cc]);
      buf[256 + cc] = bf2f(Aa[base + cc]);
    } else if (sel == 1){
      buf[64 + cc]  = expf(-bf2f(UX[base + cc]));   // wt = exp(-exp(w))
      buf[320 + cc] = bf2f(Bv[base + cc]);
    } else if (sel == 2){
      buf[128 + cc] = bf2f(KFt[base + cc]);
    } else {
      buf[192 + cc] = bf2f(Vt[base + cc]);
    }
    __syncthreads();
    const float* q_l = buf;
    const float* w_l = buf + 64;
    const float* k_l = buf + 128;
    const float* v_l = buf + 192;
    const float* a_l = buf + 256;
    const float* b_l = buf + 320;

    float sa = 0.f;
    #pragma unroll
    for (int jj = 0; jj < 16; ++jj) sa += S[jj] * a_l[j0 + jj];
    sa += __shfl_xor(sa, 1, 4);
    sa += __shfl_xor(sa, 2, 4);
    float vi = v_l[i];
    float yp = 0.f;
    #pragma unroll
    for (int jj = 0; jj < 16; ++jj){
      int j = j0 + jj;
      S[jj] = S[jj] * w_l[j] + sa * b_l[j] + vi * k_l[j];
      yp += S[jj] * q_l[j];
    }
    yp += __shfl_xor(yp, 1, 4);
    yp += __shfl_xor(yp, 2, 4);
    if (jg == 0) Y[base + i] = f2bf(yp);
  }
}

// ---------------------------------------------------------------------------
// Post: GroupNorm + bonus (r.k*faaaa)v + gate -> YG (bf16)
// ---------------------------------------------------------------------------
__global__ __launch_bounds__(256) void k_post(const bf16u* __restrict__ Y,
                                              const bf16u* __restrict__ R,
                                              const bf16u* __restrict__ KFt,
                                              const bf16u* __restrict__ Vt,
                                              const float* __restrict__ GT,
                                              const float* __restrict__ gw2,
                                              const float* __restrict__ lnw,
                                              const float* __restrict__ lnb,
                                              const float* __restrict__ faaaa,
                                              bf16u* __restrict__ YG){
  int n = blockIdx.x, tid = threadIdx.x;
  __shared__ float gt_l[128];
  if (tid < 128) gt_l[tid] = GT[(size_t)n * 128 + tid];
  __syncthreads();
  int c = tid * 4;
  size_t e = (size_t)n * CC + c;

  float ya[4]; ld4bf(Y + e, ya);
  float s = ya[0] + ya[1] + ya[2] + ya[3];
  s = red16(s);
  float mu = s * (1.f / 64.f);
  float d[4], vs = 0.f;
  #pragma unroll
  for (int i = 0; i < 4; ++i){ d[i] = ya[i] - mu; vs += d[i] * d[i]; }
  vs = red16(vs);
  float rstd = rsqrtf(vs * (1.f / 64.f) + EPSGN);

  float r4[4], k4[4], va[4], fa4[4];
  ld4bf(R + e, r4); ld4bf(KFt + e, k4); ld4bf(Vt + e, va);
  ld4f(faaaa + c, fa4);
  float rk = r4[0]*k4[0]*fa4[0] + r4[1]*k4[1]*fa4[1] + r4[2]*k4[2]*fa4[2] + r4[3]*k4[3]*fa4[3];
  rk = red16(rk);

  float lw4[4], lb4[4];
  ld4f(lnw + c, lw4); ld4f(lnb + c, lb4);
  float yn[4];
  #pragma unroll
  for (int i = 0; i < 4; ++i)
    yn[i] = d[i] * rstd * lw4[i] + lb4[i] + rk * va[i];

  float g[4] = {0,0,0,0};
  #pragma unroll 8
  for (int j = 0; j < 128; ++j){
    float gl = gt_l[j];
    float wv[4]; ld4f(gw2 + (size_t)j * CC + c, wv);
    g[0] += gl*wv[0]; g[1] += gl*wv[1]; g[2] += gl*wv[2]; g[3] += gl*wv[3];
  }
  float o[4] = {yn[0]*g[0], yn[1]*g[1], yn[2]*g[2], yn[3]*g[3]};
  st4bf(YG + e, o);
}

// ---------------------------------------------------------------------------
extern "C" void kernel_launch(void* const* d_in, const int* in_sizes, int n_in,
                              void* d_out, int out_size, void* d_ws, size_t ws_size,
                              hipStream_t stream){
  (void)in_sizes; (void)n_in; (void)out_size; (void)ws_size;
  const float* x        = (const float*)d_in[0];
  const float* tmx      = (const float*)d_in[1];
  const float* tmaa     = (const float*)d_in[2];
  const float* maa_w1   = (const float*)d_in[3];
  const float* maa_w2   = (const float*)d_in[4];
  const float* decay_w1 = (const float*)d_in[5];
  const float* decay_w2 = (const float*)d_in[6];
  const float* aaa_w1   = (const float*)d_in[7];
  const float* aaa_w2   = (const float*)d_in[8];
  const float* kkk_w1   = (const float*)d_in[9];
  const float* kkk_w2   = (const float*)d_in[10];
  const float* gate_w1  = (const float*)d_in[11];
  const float* gate_w2  = (const float*)d_in[12];
  const float* ma_w1    = (const float*)d_in[13];
  const float* ma_w2    = (const float*)d_in[14];
  const float* mk_w1    = (const float*)d_in[15];
  const float* mk_w2    = (const float*)d_in[16];
  const float* t_decay  = (const float*)d_in[17];
  const float* t_faaaa  = (const float*)d_in[18];
  const float* t_aaaaa  = (const float*)d_in[19];
  const float* t_misc_a = (const float*)d_in[20];
  const float* t_misc_k = (const float*)d_in[21];
  const float* Wr       = (const float*)d_in[22];
  const float* Wk       = (const float*)d_in[23];
  const float* Wv       = (const float*)d_in[24];
  const float* Wo       = (const float*)d_in[25];
  const float* ln_w     = (const float*)d_in[26];
  const float* ln_b     = (const float*)d_in[27];

  // Layout: 7 bf16 slots of 8MiB + f32 smalls; total 62 MiB.
  // S0: MIX -> X0(xrg) -> KKN -> YG | S1: X1(xwa) -> Bb | S2: X2(xk) -> UX
  // S3: X3(xv) -> Y(bf16) | S4: R | S5: K0 -> KF (in-place) | S6: V
  bf16u* bw  = (bf16u*)d_ws;
  bf16u* MIX = bw + 0*SLOT;
  bf16u* X0  = bw + 0*SLOT;
  bf16u* KKN = bw + 0*SLOT;
  bf16u* YG  = bw + 0*SLOT;
  bf16u* X1  = bw + 1*SLOT;
  bf16u* Bb  = bw + 1*SLOT;
  bf16u* X2  = bw + 2*SLOT;
  bf16u* UX  = bw + 2*SLOT;
  bf16u* X3  = bw + 3*SLOT;
  bf16u* Yb  = bw + 3*SLOT;
  bf16u* R   = bw + 4*SLOT;
  bf16u* K0  = bw + 5*SLOT;   // becomes KF
  bf16u* V   = bw + 6*SLOT;
  char*  wsb = (char*)d_ws;
  float* LO  = (float*)(wsb + (56ull<<20));   // [N,128] f32, 2MiB
  float* GT  = (float*)(wsb + (58ull<<20));   // [N,128] f32, 2MiB
  float* DT  = (float*)(wsb + (60ull<<20));   // [N,64]  f32, 1MiB
  float* KT  = (float*)(wsb + (61ull<<20));   // [N,16] x4, 1MiB total
  float* AT  = KT + (size_t)NNtok*16;
  float* MA  = AT + (size_t)NNtok*16;
  float* MK  = MA + (size_t)NNtok*16;

  // 1. mix
  k_prep<<<4096, 256, 0, stream>>>(x, tmx, MIX);
  // 2. lo = tanh(mix @ maa_w1^T)  [N,128]
  k_gemm_nt<128,64,16,8,4,1,false><<<dim3(2,32),256,0,stream>>>(MIX, maa_w1, LO, 128, CC);
  // 3. xm[g]
  k_xm<<<4096, 256, 0, stream>>>(x, LO, tmaa, maa_w2, X0, X1, X2, X3);
  // 4. big projections (bf16 out)
  k_gemm_nt<128,64,16,8,4,0,true><<<dim3(16,32),256,0,stream>>>(X0, Wr, R,  CC, CC);
  k_gemm_nt<128,64,16,8,4,0,true><<<dim3(16,32),256,0,stream>>>(X2, Wk, K0, CC, CC);
  k_gemm_nt<128,64,16,8,4,0,true><<<dim3(16,32),256,0,stream>>>(X3, Wv, V,  CC, CC);
  // 5. small first-stage projections (f32 out)
  k_gemm_nt<128,64,16,8,4,1,false><<<dim3(2,32),256,0,stream>>>(X0, gate_w1,  GT, 128, CC);
  k_gemm_nt<64, 64,16,4,4,1,false><<<dim3(1,64),256,0,stream>>>(X1, decay_w1, DT,  64, CC);
  k_gemm_nt<128,16,16,8,1,1,false><<<dim3(1,32),256,0,stream>>>(X2, kkk_w1,   KT,  16, CC);
  k_gemm_nt<128,16,16,8,1,0,false><<<dim3(1,32),256,0,stream>>>(X1, aaa_w1,   AT,  16, CC);
  k_gemm_nt<128,16,16,8,1,0,false><<<dim3(1,32),256,0,stream>>>(X1, ma_w1,    MA,  16, CC);
  k_gemm_nt<128,16,16,8,1,0,false><<<dim3(1,32),256,0,stream>>>(X2, mk_w1,    MK,  16, CC);
  // 6. fused elementwise
  k_elem<<<4096, 256, 0, stream>>>(K0, DT, KT, AT, MA, MK,
                                   decay_w2, kkk_w2, aaa_w2, ma_w2, mk_w2,
                                   t_decay, t_aaaaa, t_misc_a, t_misc_k,
                                   KKN, Bb, UX);
  // 7. delta-rule recurrence
  k_rec<<<64, 256, 0, stream>>>(R, UX, K0, V, KKN, Bb, Yb);
  // 8. groupnorm + bonus + gate
  k_post<<<4096, 256, 0, stream>>>(Yb, R, K0, V, GT, gate_w2, ln_w, ln_b, t_faaaa, YG);
  // 9. out = yg @ Wo^T  -> f32 output
  k_gemm_nt<128,64,16,8,4,0,false><<<dim3(16,32),256,0,stream>>>(YG, Wo, d_out, CC, CC);
}

// Round 6
// 2374.499 us; speedup vs baseline: 1.4107x; 1.4107x over previous
//
#include <hip/hip_runtime.h>
#include <cstdint>
#include <cstddef>

// Problem constants
#define BB   4
#define TT   1024
#define CC   1024
#define HH   16
#define HSS  64
#define NNtok 4096            // B*T
#define EPSGN 0.00064f

typedef unsigned short bf16u;
typedef __attribute__((ext_vector_type(8))) short short8;
typedef __attribute__((ext_vector_type(4))) float f32x4;
#define SLOT 4194304ull       // elements per 8MiB bf16 slot (= NNtok*CC)

__device__ __forceinline__ float bf2f(bf16u u){
  union { unsigned int i; float f; } cv; cv.i = ((unsigned int)u) << 16; return cv.f;
}
__device__ __forceinline__ unsigned short f2bfbits(unsigned int x){
  return (unsigned short)((x + 0x7fffu + ((x >> 16) & 1u)) >> 16);   // RNE
}
__device__ __forceinline__ bf16u f2bf(float f){
  union { float f; unsigned int i; } cv; cv.f = f;
  return f2bfbits(cv.i);
}
__device__ __forceinline__ void ld4bf(const bf16u* p, float* o){
  ushort4 u = *reinterpret_cast<const ushort4*>(p);
  o[0]=bf2f(u.x); o[1]=bf2f(u.y); o[2]=bf2f(u.z); o[3]=bf2f(u.w);
}
__device__ __forceinline__ void st4bf(bf16u* p, const float* v){
  ushort4 u; u.x=f2bf(v[0]); u.y=f2bf(v[1]); u.z=f2bf(v[2]); u.w=f2bf(v[3]);
  *reinterpret_cast<ushort4*>(p) = u;
}
__device__ __forceinline__ void ld4f(const float* p, float* o){
  float4 v = *reinterpret_cast<const float4*>(p);
  o[0]=v.x; o[1]=v.y; o[2]=v.z; o[3]=v.w;
}
__device__ __forceinline__ float sigm(float x){ return 1.f / (1.f + expf(-x)); }
__device__ __forceinline__ float red16(float v){
  v += __shfl_xor(v, 1, 16); v += __shfl_xor(v, 2, 16);
  v += __shfl_xor(v, 4, 16); v += __shfl_xor(v, 8, 16);
  return v;
}
__device__ __forceinline__ void unpack2(unsigned int w, float* o){
  union { unsigned int i; float f; } lo, hi;
  lo.i = w << 16; hi.i = w & 0xffff0000u;
  o[0] = lo.f; o[1] = hi.f;
}
__device__ __forceinline__ void unpack16(uint4 a, uint4 b, float* o){
  unpack2(a.x, o+0);  unpack2(a.y, o+2);  unpack2(a.z, o+4);  unpack2(a.w, o+6);
  unpack2(b.x, o+8);  unpack2(b.y, o+10); unpack2(b.z, o+12); unpack2(b.w, o+14);
}

// ---------------------------------------------------------------------------
// mix = x + (x[t-1]-x[t])*time_maa_x  (x[-1]=0), stored bf16
// ---------------------------------------------------------------------------
__global__ __launch_bounds__(256) void k_prep(const float* __restrict__ x,
                                              const float* __restrict__ tmx,
                                              bf16u* __restrict__ MIX){
  int e = (blockIdx.x * 256 + threadIdx.x) * 4;
  int n = e >> 10;
  int c = e & (CC - 1);
  int t = n & (TT - 1);
  float xf[4]; ld4f(x + e, xf);
  float pf[4] = {0.f, 0.f, 0.f, 0.f};
  if (t > 0) ld4f(x + e - CC, pf);
  float tm[4]; ld4f(tmx + c, tm);
  float mv[4];
  #pragma unroll
  for (int i = 0; i < 4; ++i) mv[i] = xf[i] + (pf[i] - xf[i]) * tm[i];
  st4bf(MIX + e, mv);
}

// ---------------------------------------------------------------------------
// MFMA NT GEMM: OUT[M,Nd] = X[M,K](bf16) @ W[Nd,K]^T, W given as up to 3
// concatenated f32 row-blocks: rows [0,na) from Wa, [na,nab) from Wb,
// [nab,Nd) from Wc. tanh applied to cols < act_n. OB: bf16 out else f32.
// 128x128 tile, 4 waves (2x2), BK=32, v_mfma_f32_16x16x32_bf16.
// A/B frag: [row=lane&15][k=quad*8+j]; C/D: col=lane&15, row=quad*4+reg.
// ---------------------------------------------------------------------------
template<bool OB>
__global__ __launch_bounds__(256) void k_gemm_mfma(const bf16u* __restrict__ X,
                                                   const float* __restrict__ Wa,
                                                   const float* __restrict__ Wb,
                                                   const float* __restrict__ Wc,
                                                   int na, int nab,
                                                   void* __restrict__ OUTv,
                                                   int Nd, int Kd, int act_n){
  __shared__ short As[128 * 40];
  __shared__ short Bs[128 * 40];
  const int tid  = threadIdx.x;
  const int lane = tid & 63;
  const int wv   = tid >> 6;
  const int wm   = wv >> 1, wn = wv & 1;
  const int bn0  = blockIdx.x * 128;
  const int bm0  = blockIdx.y * 128;
  const int l15  = lane & 15;
  const int quad = lane >> 4;

  f32x4 acc[4][4];
  #pragma unroll
  for (int mi = 0; mi < 4; ++mi)
    #pragma unroll
    for (int ni = 0; ni < 4; ++ni)
      #pragma unroll
      for (int rg = 0; rg < 4; ++rg) acc[mi][ni][rg] = 0.f;

  const int r    = tid >> 1;            // 0..127 staging row
  const int half = (tid & 1) * 16;      // k sub-offset

  int rr = bn0 + r;
  const float* wsrc = nullptr;
  if (rr < na)        wsrc = Wa + (size_t)rr * Kd;
  else if (rr < nab)  wsrc = Wb + (size_t)(rr - na) * Kd;
  else if (rr < Nd)   wsrc = Wc + (size_t)(rr - nab) * Kd;
  const bf16u* xsrc = X + (size_t)(bm0 + r) * Kd;

  for (int k0 = 0; k0 < Kd; k0 += 32){
    uint4 xa = *(const uint4*)(xsrc + k0 + half);
    uint4 xb = *(const uint4*)(xsrc + k0 + half + 8);
    uint4 w0 = make_uint4(0,0,0,0), w1 = w0, w2 = w0, w3 = w0;
    if (wsrc){
      w0 = *(const uint4*)(wsrc + k0 + half);
      w1 = *(const uint4*)(wsrc + k0 + half + 4);
      w2 = *(const uint4*)(wsrc + k0 + half + 8);
      w3 = *(const uint4*)(wsrc + k0 + half + 12);
    }
    union { unsigned short s[8]; uint4 v; } p0, p1;
    p0.s[0]=f2bfbits(w0.x); p0.s[1]=f2bfbits(w0.y); p0.s[2]=f2bfbits(w0.z); p0.s[3]=f2bfbits(w0.w);
    p0.s[4]=f2bfbits(w1.x); p0.s[5]=f2bfbits(w1.y); p0.s[6]=f2bfbits(w1.z); p0.s[7]=f2bfbits(w1.w);
    p1.s[0]=f2bfbits(w2.x); p1.s[1]=f2bfbits(w2.y); p1.s[2]=f2bfbits(w2.z); p1.s[3]=f2bfbits(w2.w);
    p1.s[4]=f2bfbits(w3.x); p1.s[5]=f2bfbits(w3.y); p1.s[6]=f2bfbits(w3.z); p1.s[7]=f2bfbits(w3.w);

    *(uint4*)&As[r * 40 + half]     = xa;
    *(uint4*)&As[r * 40 + half + 8] = xb;
    *(uint4*)&Bs[r * 40 + half]     = p0.v;
    *(uint4*)&Bs[r * 40 + half + 8] = p1.v;
    __syncthreads();

    short8 af[4], bfg[4];
    #pragma unroll
    for (int mi = 0; mi < 4; ++mi)
      af[mi] = *(const short8*)&As[(wm*64 + mi*16 + l15) * 40 + quad*8];
    #pragma unroll
    for (int ni = 0; ni < 4; ++ni)
      bfg[ni] = *(const short8*)&Bs[(wn*64 + ni*16 + l15) * 40 + quad*8];
    #pragma unroll
    for (int mi = 0; mi < 4; ++mi)
      #pragma unroll
      for (int ni = 0; ni < 4; ++ni)
        acc[mi][ni] = __builtin_amdgcn_mfma_f32_16x16x32_bf16(af[mi], bfg[ni], acc[mi][ni], 0, 0, 0);
    __syncthreads();
  }

  #pragma unroll
  for (int mi = 0; mi < 4; ++mi){
    #pragma unroll
    for (int ni = 0; ni < 4; ++ni){
      int col = bn0 + wn*64 + ni*16 + l15;
      if (col >= Nd) continue;
      #pragma unroll
      for (int rg = 0; rg < 4; ++rg){
        int row = bm0 + wm*64 + mi*16 + quad*4 + rg;
        float v = acc[mi][ni][rg];
        if (col < act_n) v = tanhf(v);
        if (OB) ((bf16u*)OUTv)[(size_t)row * Nd + col] = f2bf(v);
        else    ((float*)OUTv)[(size_t)row * Nd + col] = v;
      }
    }
  }
}

// ---------------------------------------------------------------------------
// xm[g] = x + xx*(lo_g @ maa_w2[g] + time_maa[g]), xx recomputed from x
// ---------------------------------------------------------------------------
__global__ __launch_bounds__(256) void k_xm(const float* __restrict__ x,
                                            const float* __restrict__ LO,
                                            const float* __restrict__ tmaa,
                                            const float* __restrict__ mw2,
                                            bf16u* __restrict__ X0, bf16u* __restrict__ X1,
                                            bf16u* __restrict__ X2, bf16u* __restrict__ X3){
  int n = blockIdx.x, tid = threadIdx.x;
  __shared__ float lo_l[128];
  if (tid < 128) lo_l[tid] = LO[(size_t)n * 128 + tid];
  __syncthreads();
  int c = tid * 4;
  int t = n & (TT - 1);
  size_t e = (size_t)n * CC + c;
  float xf[4]; ld4f(x + e, xf);
  float pf[4] = {0.f, 0.f, 0.f, 0.f};
  if (t > 0) ld4f(x + e - CC, pf);
  float xxa[4];
  #pragma unroll
  for (int i = 0; i < 4; ++i) xxa[i] = pf[i] - xf[i];

  bf16u* outs[4] = {X0, X1, X2, X3};
  #pragma unroll
  for (int g = 0; g < 4; ++g){
    float a[4]; ld4f(tmaa + (size_t)g * CC + c, a);
    #pragma unroll 8
    for (int j = 0; j < 32; ++j){
      float l = lo_l[g * 32 + j];
      float wvv[4]; ld4f(mw2 + (size_t)(g * 32 + j) * CC + c, wvv);
      a[0] += l * wvv[0]; a[1] += l * wvv[1]; a[2] += l * wvv[2]; a[3] += l * wvv[3];
    }
    float rv[4];
    #pragma unroll
    for (int i = 0; i < 4; ++i) rv[i] = xf[i] + xxa[i] * a[i];
    st4bf(outs[g] + e, rv);
  }
}

// ---------------------------------------------------------------------------
// Fused elementwise + small LoRA second matmuls.
// P1[n,96] = DT(tanh)|AT|MA ; P2[n,32] = KT(tanh)|MK
// Outputs: KF (in-place over K0), KKN, Bb, UX = exp(w)  (all bf16)
// ---------------------------------------------------------------------------
__global__ __launch_bounds__(256) void k_elem(bf16u* __restrict__ K0,
    const float* __restrict__ P1, const float* __restrict__ P2,
    const float* __restrict__ dw2, const float* __restrict__ kw2,
    const float* __restrict__ aw2, const float* __restrict__ maw2,
    const float* __restrict__ mkw2,
    const float* __restrict__ td,  const float* __restrict__ taa,
    const float* __restrict__ tma, const float* __restrict__ tmk,
    bf16u* __restrict__ KKN, bf16u* __restrict__ Bb, bf16u* __restrict__ UX){
  int n = blockIdx.x, tid = threadIdx.x;
  __shared__ float sm[96];    // dt 0..63 | at 64..79 | ma 80..95
  __shared__ float sm2[32];   // kt 0..15 | mk 16..31
  if (tid < 96)       sm[tid]        = P1[(size_t)n * 96 + tid];
  else if (tid < 128) sm2[tid - 96]  = P2[(size_t)n * 32 + (tid - 96)];
  __syncthreads();
  int c = tid * 4;
  size_t e = (size_t)n * CC + c;

  float w2a[4] = {0,0,0,0};
  #pragma unroll 8
  for (int j = 0; j < 64; ++j){
    float d = sm[j];
    float wvv[4]; ld4f(dw2 + (size_t)j * CC + c, wvv);
    w2a[0] += d*wvv[0]; w2a[1] += d*wvv[1]; w2a[2] += d*wvv[2]; w2a[3] += d*wvv[3];
  }
  float kkk4[4] = {0,0,0,0}, aa4[4] = {0,0,0,0}, mam4[4] = {0,0,0,0}, mkm4[4] = {0,0,0,0};
  #pragma unroll
  for (int j = 0; j < 16; ++j){
    float wvv[4];
    float s;
    s = sm2[j];      ld4f(kw2  + (size_t)j * CC + c, wvv);
    kkk4[0]+=s*wvv[0]; kkk4[1]+=s*wvv[1]; kkk4[2]+=s*wvv[2]; kkk4[3]+=s*wvv[3];
    s = sm[64 + j];  ld4f(aw2  + (size_t)j * CC + c, wvv);
    aa4[0]+=s*wvv[0];  aa4[1]+=s*wvv[1];  aa4[2]+=s*wvv[2];  aa4[3]+=s*wvv[3];
    s = sm[80 + j];  ld4f(maw2 + (size_t)j * CC + c, wvv);
    mam4[0]+=s*wvv[0]; mam4[1]+=s*wvv[1]; mam4[2]+=s*wvv[2]; mam4[3]+=s*wvv[3];
    s = sm2[16 + j]; ld4f(mkw2 + (size_t)j * CC + c, wvv);
    mkm4[0]+=s*wvv[0]; mkm4[1]+=s*wvv[1]; mkm4[2]+=s*wvv[2]; mkm4[3]+=s*wvv[3];
  }

  float k0a[4]; ld4bf(K0 + e, k0a);
  float td4[4], taa4[4], tma4[4], tmk4[4];
  ld4f(td + c, td4); ld4f(taa + c, taa4);
  ld4f(tma + c, tma4); ld4f(tmk + c, tmk4);

  float kkv[4];
  float ssq = 0.f;
  #pragma unroll
  for (int i = 0; i < 4; ++i){ kkv[i] = k0a[i] + kkk4[i]; ssq += kkv[i]*kkv[i]; }
  ssq = red16(ssq);
  float rinv = 1.f / fmaxf(sqrtf(ssq), 1e-12f);

  float kkn[4], outb[4], outkf[4], outu[4];
  #pragma unroll
  for (int i = 0; i < 4; ++i){
    float z  = td4[i] + w2a[i];
    float nz = -z;
    float sp = (nz > 15.f) ? nz : log1pf(expf(nz));
    float w  = -sp - 0.5f;               // <= -0.5
    float av = sigm(taa4[i] + aa4[i]);
    float mav = sigm(tma4[i] + mam4[i]);
    float mkv = sigm(tmk4[i] + mkm4[i]);
    kkn[i]  = kkv[i] * rinv;
    outb[i] = -kkn[i] * av;
    outkf[i]= k0a[i] * (mav + av * (1.f - mav)) * expf(w * mkv);
    outu[i] = expf(w);                   // in (0, 0.61]
  }
  st4bf(KKN + e, kkn);
  st4bf(Bb  + e, outb);
  st4bf(K0  + e, outkf);   // in-place: K0 -> KF
  st4bf(UX  + e, outu);
}

// ---------------------------------------------------------------------------
// Recurrence, barrier-free: one block per (b,h); thread (i=tid>>2, jg=tid&3)
// owns S[i][jg*16..+15]. Register-resident distance-2 prefetch of q,k,a,b
// slices; wt = exp(-exp(w)) shared per-wave via private LDS (wave-synchronous,
// no __syncthreads anywhere).
// ---------------------------------------------------------------------------
__global__ __launch_bounds__(256, 1) void k_rec(const bf16u* __restrict__ Q,
                                                const bf16u* __restrict__ UX,
                                                const bf16u* __restrict__ KFt,
                                                const bf16u* __restrict__ Vt,
                                                const bf16u* __restrict__ Aa,
                                                const bf16u* __restrict__ Bv,
                                                bf16u* __restrict__ Y){
  int bh = blockIdx.x;
  int b = bh >> 4, h = bh & 15;
  int tid  = threadIdx.x;
  int lane = tid & 63, wv = tid >> 6;
  int i  = tid >> 2, jg = tid & 3, j0 = jg * 16;
  __shared__ float wls[4][64];
  float S[16];
  #pragma unroll
  for (int u = 0; u < 16; ++u) S[u] = 0.f;
  size_t base0 = (size_t)(b * TT) * CC + h * HSS;

  uint4 pq[2][2], pk[2][2], pa[2][2], pb[2][2];
  bf16u pv[2], pu[2];
  #pragma unroll
  for (int s = 0; s < 2; ++s){
    size_t bn = base0 + (size_t)s * CC;
    const uint4* qp = (const uint4*)(Q   + bn + j0); pq[s][0] = qp[0]; pq[s][1] = qp[1];
    const uint4* kp = (const uint4*)(KFt + bn + j0); pk[s][0] = kp[0]; pk[s][1] = kp[1];
    const uint4* ap = (const uint4*)(Aa  + bn + j0); pa[s][0] = ap[0]; pa[s][1] = ap[1];
    const uint4* bp = (const uint4*)(Bv  + bn + j0); pb[s][0] = bp[0]; pb[s][1] = bp[1];
    pv[s] = Vt[bn + i]; pu[s] = UX[bn + lane];
  }

  size_t base = base0;
  for (int t = 0; t < TT; ++t, base += CC){
    int s = t & 1;
    float uu = bf2f(pu[s]);
    wls[wv][lane] = expf(-uu);          // wt = exp(-exp(w)), wave-private share

    float aj[16], kj[16], bj[16], qj[16];
    unpack16(pa[s][0], pa[s][1], aj);
    unpack16(pk[s][0], pk[s][1], kj);
    unpack16(pb[s][0], pb[s][1], bj);
    unpack16(pq[s][0], pq[s][1], qj);
    float vi = bf2f(pv[s]);

    float sa = 0.f;
    #pragma unroll
    for (int jj = 0; jj < 16; ++jj) sa += S[jj] * aj[jj];
    sa += __shfl_xor(sa, 1, 4);
    sa += __shfl_xor(sa, 2, 4);

    float wj[16];
    #pragma unroll
    for (int jj = 0; jj < 16; ++jj) wj[jj] = wls[wv][j0 + jj];

    float yp = 0.f;
    #pragma unroll
    for (int jj = 0; jj < 16; ++jj){
      S[jj] = fmaf(S[jj], wj[jj], fmaf(sa, bj[jj], vi * kj[jj]));
      yp += S[jj] * qj[jj];
    }
    yp += __shfl_xor(yp, 1, 4);
    yp += __shfl_xor(yp, 2, 4);
    if (jg == 0) Y[base + i] = f2bf(yp);

    if (t + 2 < TT){
      size_t bn = base + 2 * CC;
      const uint4* qp = (const uint4*)(Q   + bn + j0); pq[s][0] = qp[0]; pq[s][1] = qp[1];
      const uint4* kp = (const uint4*)(KFt + bn + j0); pk[s][0] = kp[0]; pk[s][1] = kp[1];
      const uint4* ap = (const uint4*)(Aa  + bn + j0); pa[s][0] = ap[0]; pa[s][1] = ap[1];
      const uint4* bp = (const uint4*)(Bv  + bn + j0); pb[s][0] = bp[0]; pb[s][1] = bp[1];
      pv[s] = Vt[bn + i]; pu[s] = UX[bn + lane];
    }
  }
}

// ---------------------------------------------------------------------------
// Post: GroupNorm + bonus (r.k*faaaa)v + gate -> YG (bf16)
// ---------------------------------------------------------------------------
__global__ __launch_bounds__(256) void k_post(const bf16u* __restrict__ Y,
                                              const bf16u* __restrict__ R,
                                              const bf16u* __restrict__ KFt,
                                              const bf16u* __restrict__ Vt,
                                              const float* __restrict__ GT,
                                              const float* __restrict__ gw2,
                                              const float* __restrict__ lnw,
                                              const float* __restrict__ lnb,
                                              const float* __restrict__ faaaa,
                                              bf16u* __restrict__ YG){
  int n = blockIdx.x, tid = threadIdx.x;
  __shared__ float gt_l[128];
  if (tid < 128) gt_l[tid] = GT[(size_t)n * 128 + tid];
  __syncthreads();
  int c = tid * 4;
  size_t e = (size_t)n * CC + c;

  float ya[4]; ld4bf(Y + e, ya);
  float s = ya[0] + ya[1] + ya[2] + ya[3];
  s = red16(s);
  float mu = s * (1.f / 64.f);
  float d[4], vs = 0.f;
  #pragma unroll
  for (int i = 0; i < 4; ++i){ d[i] = ya[i] - mu; vs += d[i] * d[i]; }
  vs = red16(vs);
  float rstd = rsqrtf(vs * (1.f / 64.f) + EPSGN);

  float r4[4], k4[4], va[4], fa4[4];
  ld4bf(R + e, r4); ld4bf(KFt + e, k4); ld4bf(Vt + e, va);
  ld4f(faaaa + c, fa4);
  float rk = r4[0]*k4[0]*fa4[0] + r4[1]*k4[1]*fa4[1] + r4[2]*k4[2]*fa4[2] + r4[3]*k4[3]*fa4[3];
  rk = red16(rk);

  float lw4[4], lb4[4];
  ld4f(lnw + c, lw4); ld4f(lnb + c, lb4);
  float yn[4];
  #pragma unroll
  for (int i = 0; i < 4; ++i)
    yn[i] = d[i] * rstd * lw4[i] + lb4[i] + rk * va[i];

  float g[4] = {0,0,0,0};
  #pragma unroll 8
  for (int j = 0; j < 128; ++j){
    float gl = gt_l[j];
    float wvv[4]; ld4f(gw2 + (size_t)j * CC + c, wvv);
    g[0] += gl*wvv[0]; g[1] += gl*wvv[1]; g[2] += gl*wvv[2]; g[3] += gl*wvv[3];
  }
  float o[4] = {yn[0]*g[0], yn[1]*g[1], yn[2]*g[2], yn[3]*g[3]};
  st4bf(YG + e, o);
}

// ---------------------------------------------------------------------------
extern "C" void kernel_launch(void* const* d_in, const int* in_sizes, int n_in,
                              void* d_out, int out_size, void* d_ws, size_t ws_size,
                              hipStream_t stream){
  (void)in_sizes; (void)n_in; (void)out_size; (void)ws_size;
  const float* x        = (const float*)d_in[0];
  const float* tmx      = (const float*)d_in[1];
  const float* tmaa     = (const float*)d_in[2];
  const float* maa_w1   = (const float*)d_in[3];
  const float* maa_w2   = (const float*)d_in[4];
  const float* decay_w1 = (const float*)d_in[5];
  const float* decay_w2 = (const float*)d_in[6];
  const float* aaa_w1   = (const float*)d_in[7];
  const float* aaa_w2   = (const float*)d_in[8];
  const float* kkk_w1   = (const float*)d_in[9];
  const float* kkk_w2   = (const float*)d_in[10];
  const float* gate_w1  = (const float*)d_in[11];
  const float* gate_w2  = (const float*)d_in[12];
  const float* ma_w1    = (const float*)d_in[13];
  const float* ma_w2    = (const float*)d_in[14];
  const float* mk_w1    = (const float*)d_in[15];
  const float* mk_w2    = (const float*)d_in[16];
  const float* t_decay  = (const float*)d_in[17];
  const float* t_faaaa  = (const float*)d_in[18];
  const float* t_aaaaa  = (const float*)d_in[19];
  const float* t_misc_a = (const float*)d_in[20];
  const float* t_misc_k = (const float*)d_in[21];
  const float* Wr       = (const float*)d_in[22];
  const float* Wk       = (const float*)d_in[23];
  const float* Wv       = (const float*)d_in[24];
  const float* Wo       = (const float*)d_in[25];
  const float* ln_w     = (const float*)d_in[26];
  const float* ln_b     = (const float*)d_in[27];

  // Layout: 7 bf16 slots of 8MiB + f32 smalls; total 62 MiB.
  // S0: MIX -> X0(xrg) -> KKN -> YG | S1: X1(xwa) -> Bb | S2: X2(xk) -> UX
  // S3: X3(xv) -> Y(bf16) | S4: R | S5: K0 -> KF (in-place) | S6: V
  bf16u* bw  = (bf16u*)d_ws;
  bf16u* MIX = bw + 0*SLOT;
  bf16u* X0  = bw + 0*SLOT;
  bf16u* KKN = bw + 0*SLOT;
  bf16u* YG  = bw + 0*SLOT;
  bf16u* X1  = bw + 1*SLOT;
  bf16u* Bb  = bw + 1*SLOT;
  bf16u* X2  = bw + 2*SLOT;
  bf16u* UX  = bw + 2*SLOT;
  bf16u* X3  = bw + 3*SLOT;
  bf16u* Yb  = bw + 3*SLOT;
  bf16u* R   = bw + 4*SLOT;
  bf16u* K0  = bw + 5*SLOT;   // becomes KF
  bf16u* V   = bw + 6*SLOT;
  char*  wsb = (char*)d_ws;
  float* LO  = (float*)(wsb + (56ull<<20));   // [N,128] f32, 2MiB
  float* GT  = (float*)(wsb + (58ull<<20));   // [N,128] f32, 2MiB
  float* P1  = (float*)(wsb + (60ull<<20));   // [N,96]  f32, 1.5MiB (DT|AT|MA)
  float* P2  = (float*)(wsb + (61ull<<20) + (512ull<<10));  // [N,32] f32, 0.5MiB (KT|MK)

  // 1. mix
  k_prep<<<4096, 256, 0, stream>>>(x, tmx, MIX);
  // 2. lo = tanh(mix @ maa_w1^T)  [N,128]
  k_gemm_mfma<false><<<dim3(1,32),256,0,stream>>>(MIX, maa_w1, maa_w1, maa_w1,
                                                  128, 128, LO, 128, CC, 128);
  // 3. xm[g]
  k_xm<<<4096, 256, 0, stream>>>(x, LO, tmaa, maa_w2, X0, X1, X2, X3);
  // 4. big projections (bf16 out)
  k_gemm_mfma<true><<<dim3(8,32),256,0,stream>>>(X0, Wr, Wr, Wr, CC, CC, R,  CC, CC, 0);
  k_gemm_mfma<true><<<dim3(8,32),256,0,stream>>>(X2, Wk, Wk, Wk, CC, CC, K0, CC, CC, 0);
  k_gemm_mfma<true><<<dim3(8,32),256,0,stream>>>(X3, Wv, Wv, Wv, CC, CC, V,  CC, CC, 0);
  // 5. small first-stage projections (fused, f32 out)
  k_gemm_mfma<false><<<dim3(1,32),256,0,stream>>>(X0, gate_w1, gate_w1, gate_w1,
                                                  128, 128, GT, 128, CC, 128);
  k_gemm_mfma<false><<<dim3(1,32),256,0,stream>>>(X1, decay_w1, aaa_w1, ma_w1,
                                                  64, 80, P1, 96, CC, 64);
  k_gemm_mfma<false><<<dim3(1,32),256,0,stream>>>(X2, kkk_w1, mk_w1, mk_w1,
                                                  16, 32, P2, 32, CC, 16);
  // 6. fused elementwise
  k_elem<<<4096, 256, 0, stream>>>(K0, P1, P2,
                                   decay_w2, kkk_w2, aaa_w2, ma_w2, mk_w2,
                                   t_decay, t_aaaaa, t_misc_a, t_misc_k,
                                   KKN, Bb, UX);
  // 7. delta-rule recurrence (barrier-free, prefetch d=2)
  k_rec<<<64, 256, 0, stream>>>(R, UX, K0, V, KKN, Bb, Yb);
  // 8. groupnorm + bonus + gate
  k_post<<<4096, 256, 0, stream>>>(Yb, R, K0, V, GT, gate_w2, ln_w, ln_b, t_faaaa, YG);
  // 9. out = yg @ Wo^T  -> f32 output
  k_gemm_mfma<false><<<dim3(8,32),256,0,stream>>>(YG, Wo, Wo, Wo, CC, CC, d_out, CC, CC, 0);
}

// Round 7
// 1272.140 us; speedup vs baseline: 2.6331x; 1.8665x over previous
//
#include <hip/hip_runtime.h>
#include <cstdint>
#include <cstddef>

// Problem constants
#define BB   4
#define TT   1024
#define CC   1024
#define HH   16
#define HSS  64
#define NNtok 4096            // B*T
#define EPSGN 0.00064f

typedef unsigned short bf16u;
typedef __attribute__((ext_vector_type(8))) short short8;
typedef __attribute__((ext_vector_type(4))) float f32x4;
#define SLOT 4194304ull       // elements per 8MiB bf16 slot (= NNtok*CC)

__device__ __forceinline__ float bf2f(bf16u u){
  union { unsigned int i; float f; } cv; cv.i = ((unsigned int)u) << 16; return cv.f;
}
__device__ __forceinline__ unsigned short f2bfbits(unsigned int x){
  return (unsigned short)((x + 0x7fffu + ((x >> 16) & 1u)) >> 16);   // RNE
}
__device__ __forceinline__ bf16u f2bf(float f){
  union { float f; unsigned int i; } cv; cv.f = f;
  return f2bfbits(cv.i);
}
__device__ __forceinline__ void ld4bf(const bf16u* p, float* o){
  ushort4 u = *reinterpret_cast<const ushort4*>(p);
  o[0]=bf2f(u.x); o[1]=bf2f(u.y); o[2]=bf2f(u.z); o[3]=bf2f(u.w);
}
__device__ __forceinline__ void st4bf(bf16u* p, const float* v){
  ushort4 u; u.x=f2bf(v[0]); u.y=f2bf(v[1]); u.z=f2bf(v[2]); u.w=f2bf(v[3]);
  *reinterpret_cast<ushort4*>(p) = u;
}
__device__ __forceinline__ void ld4f(const float* p, float* o){
  float4 v = *reinterpret_cast<const float4*>(p);
  o[0]=v.x; o[1]=v.y; o[2]=v.z; o[3]=v.w;
}
__device__ __forceinline__ float sigm(float x){ return 1.f / (1.f + expf(-x)); }
__device__ __forceinline__ float red16(float v){
  v += __shfl_xor(v, 1, 16); v += __shfl_xor(v, 2, 16);
  v += __shfl_xor(v, 4, 16); v += __shfl_xor(v, 8, 16);
  return v;
}

// ---------------------------------------------------------------------------
// mix = x + (x[t-1]-x[t])*time_maa_x  (x[-1]=0), stored bf16
// ---------------------------------------------------------------------------
__global__ __launch_bounds__(256) void k_prep(const float* __restrict__ x,
                                              const float* __restrict__ tmx,
                                              bf16u* __restrict__ MIX){
  int e = (blockIdx.x * 256 + threadIdx.x) * 4;
  int n = e >> 10;
  int c = e & (CC - 1);
  int t = n & (TT - 1);
  float xf[4]; ld4f(x + e, xf);
  float pf[4] = {0.f, 0.f, 0.f, 0.f};
  if (t > 0) ld4f(x + e - CC, pf);
  float tm[4]; ld4f(tmx + c, tm);
  float mv[4];
  #pragma unroll
  for (int i = 0; i < 4; ++i) mv[i] = xf[i] + (pf[i] - xf[i]) * tm[i];
  st4bf(MIX + e, mv);
}

// ---------------------------------------------------------------------------
// MFMA NT GEMM: OUT[M,Nd] = X[M,K](bf16) @ W[Nd,K]^T, W given as up to 3
// concatenated f32 row-blocks: rows [0,na) from Wa, [na,nab) from Wb,
// [nab,Nd) from Wc. tanh applied to cols < act_n. OB: bf16 out else f32.
// 128x128 tile, 4 waves (2x2), BK=32, v_mfma_f32_16x16x32_bf16.
// ---------------------------------------------------------------------------
template<bool OB>
__global__ __launch_bounds__(256) void k_gemm_mfma(const bf16u* __restrict__ X,
                                                   const float* __restrict__ Wa,
                                                   const float* __restrict__ Wb,
                                                   const float* __restrict__ Wc,
                                                   int na, int nab,
                                                   void* __restrict__ OUTv,
                                                   int Nd, int Kd, int act_n){
  __shared__ short As[128 * 40];
  __shared__ short Bs[128 * 40];
  const int tid  = threadIdx.x;
  const int lane = tid & 63;
  const int wv   = tid >> 6;
  const int wm   = wv >> 1, wn = wv & 1;
  const int bn0  = blockIdx.x * 128;
  const int bm0  = blockIdx.y * 128;
  const int l15  = lane & 15;
  const int quad = lane >> 4;

  f32x4 acc[4][4];
  #pragma unroll
  for (int mi = 0; mi < 4; ++mi)
    #pragma unroll
    for (int ni = 0; ni < 4; ++ni)
      #pragma unroll
      for (int rg = 0; rg < 4; ++rg) acc[mi][ni][rg] = 0.f;

  const int r    = tid >> 1;            // 0..127 staging row
  const int half = (tid & 1) * 16;      // k sub-offset

  int rr = bn0 + r;
  const float* wsrc = nullptr;
  if (rr < na)        wsrc = Wa + (size_t)rr * Kd;
  else if (rr < nab)  wsrc = Wb + (size_t)(rr - na) * Kd;
  else if (rr < Nd)   wsrc = Wc + (size_t)(rr - nab) * Kd;
  const bf16u* xsrc = X + (size_t)(bm0 + r) * Kd;

  for (int k0 = 0; k0 < Kd; k0 += 32){
    uint4 xa = *(const uint4*)(xsrc + k0 + half);
    uint4 xb = *(const uint4*)(xsrc + k0 + half + 8);
    uint4 w0 = make_uint4(0,0,0,0), w1 = w0, w2 = w0, w3 = w0;
    if (wsrc){
      w0 = *(const uint4*)(wsrc + k0 + half);
      w1 = *(const uint4*)(wsrc + k0 + half + 4);
      w2 = *(const uint4*)(wsrc + k0 + half + 8);
      w3 = *(const uint4*)(wsrc + k0 + half + 12);
    }
    union { unsigned short s[8]; uint4 v; } p0, p1;
    p0.s[0]=f2bfbits(w0.x); p0.s[1]=f2bfbits(w0.y); p0.s[2]=f2bfbits(w0.z); p0.s[3]=f2bfbits(w0.w);
    p0.s[4]=f2bfbits(w1.x); p0.s[5]=f2bfbits(w1.y); p0.s[6]=f2bfbits(w1.z); p0.s[7]=f2bfbits(w1.w);
    p1.s[0]=f2bfbits(w2.x); p1.s[1]=f2bfbits(w2.y); p1.s[2]=f2bfbits(w2.z); p1.s[3]=f2bfbits(w2.w);
    p1.s[4]=f2bfbits(w3.x); p1.s[5]=f2bfbits(w3.y); p1.s[6]=f2bfbits(w3.z); p1.s[7]=f2bfbits(w3.w);

    *(uint4*)&As[r * 40 + half]     = xa;
    *(uint4*)&As[r * 40 + half + 8] = xb;
    *(uint4*)&Bs[r * 40 + half]     = p0.v;
    *(uint4*)&Bs[r * 40 + half + 8] = p1.v;
    __syncthreads();

    short8 af[4], bfg[4];
    #pragma unroll
    for (int mi = 0; mi < 4; ++mi)
      af[mi] = *(const short8*)&As[(wm*64 + mi*16 + l15) * 40 + quad*8];
    #pragma unroll
    for (int ni = 0; ni < 4; ++ni)
      bfg[ni] = *(const short8*)&Bs[(wn*64 + ni*16 + l15) * 40 + quad*8];
    #pragma unroll
    for (int mi = 0; mi < 4; ++mi)
      #pragma unroll
      for (int ni = 0; ni < 4; ++ni)
        acc[mi][ni] = __builtin_amdgcn_mfma_f32_16x16x32_bf16(af[mi], bfg[ni], acc[mi][ni], 0, 0, 0);
    __syncthreads();
  }

  #pragma unroll
  for (int mi = 0; mi < 4; ++mi){
    #pragma unroll
    for (int ni = 0; ni < 4; ++ni){
      int col = bn0 + wn*64 + ni*16 + l15;
      if (col >= Nd) continue;
      #pragma unroll
      for (int rg = 0; rg < 4; ++rg){
        int row = bm0 + wm*64 + mi*16 + quad*4 + rg;
        float v = acc[mi][ni][rg];
        if (col < act_n) v = tanhf(v);
        if (OB) ((bf16u*)OUTv)[(size_t)row * Nd + col] = f2bf(v);
        else    ((float*)OUTv)[(size_t)row * Nd + col] = v;
      }
    }
  }
}

// ---------------------------------------------------------------------------
// xm[g] = x + xx*(lo_g @ maa_w2[g] + time_maa[g]), xx recomputed from x
// ---------------------------------------------------------------------------
__global__ __launch_bounds__(256) void k_xm(const float* __restrict__ x,
                                            const float* __restrict__ LO,
                                            const float* __restrict__ tmaa,
                                            const float* __restrict__ mw2,
                                            bf16u* __restrict__ X0, bf16u* __restrict__ X1,
                                            bf16u* __restrict__ X2, bf16u* __restrict__ X3){
  int n = blockIdx.x, tid = threadIdx.x;
  __shared__ float lo_l[128];
  if (tid < 128) lo_l[tid] = LO[(size_t)n * 128 + tid];
  __syncthreads();
  int c = tid * 4;
  int t = n & (TT - 1);
  size_t e = (size_t)n * CC + c;
  float xf[4]; ld4f(x + e, xf);
  float pf[4] = {0.f, 0.f, 0.f, 0.f};
  if (t > 0) ld4f(x + e - CC, pf);
  float xxa[4];
  #pragma unroll
  for (int i = 0; i < 4; ++i) xxa[i] = pf[i] - xf[i];

  bf16u* outs[4] = {X0, X1, X2, X3};
  #pragma unroll
  for (int g = 0; g < 4; ++g){
    float a[4]; ld4f(tmaa + (size_t)g * CC + c, a);
    #pragma unroll 8
    for (int j = 0; j < 32; ++j){
      float l = lo_l[g * 32 + j];
      float wvv[4]; ld4f(mw2 + (size_t)(g * 32 + j) * CC + c, wvv);
      a[0] += l * wvv[0]; a[1] += l * wvv[1]; a[2] += l * wvv[2]; a[3] += l * wvv[3];
    }
    float rv[4];
    #pragma unroll
    for (int i = 0; i < 4; ++i) rv[i] = xf[i] + xxa[i] * a[i];
    st4bf(outs[g] + e, rv);
  }
}

// ---------------------------------------------------------------------------
// Fused elementwise + small LoRA second matmuls.
// P1[n,96] = DT(tanh)|AT|MA ; P2[n,32] = KT(tanh)|MK
// Outputs: KF (in-place over K0), KKN, Bb, UX = exp(w)  (all bf16)
// ---------------------------------------------------------------------------
__global__ __launch_bounds__(256) void k_elem(bf16u* __restrict__ K0,
    const float* __restrict__ P1, const float* __restrict__ P2,
    const float* __restrict__ dw2, const float* __restrict__ kw2,
    const float* __restrict__ aw2, const float* __restrict__ maw2,
    const float* __restrict__ mkw2,
    const float* __restrict__ td,  const float* __restrict__ taa,
    const float* __restrict__ tma, const float* __restrict__ tmk,
    bf16u* __restrict__ KKN, bf16u* __restrict__ Bb, bf16u* __restrict__ UX){
  int n = blockIdx.x, tid = threadIdx.x;
  __shared__ float sm[96];    // dt 0..63 | at 64..79 | ma 80..95
  __shared__ float sm2[32];   // kt 0..15 | mk 16..31
  if (tid < 96)       sm[tid]        = P1[(size_t)n * 96 + tid];
  else if (tid < 128) sm2[tid - 96]  = P2[(size_t)n * 32 + (tid - 96)];
  __syncthreads();
  int c = tid * 4;
  size_t e = (size_t)n * CC + c;

  float w2a[4] = {0,0,0,0};
  #pragma unroll 8
  for (int j = 0; j < 64; ++j){
    float d = sm[j];
    float wvv[4]; ld4f(dw2 + (size_t)j * CC + c, wvv);
    w2a[0] += d*wvv[0]; w2a[1] += d*wvv[1]; w2a[2] += d*wvv[2]; w2a[3] += d*wvv[3];
  }
  float kkk4[4] = {0,0,0,0}, aa4[4] = {0,0,0,0}, mam4[4] = {0,0,0,0}, mkm4[4] = {0,0,0,0};
  #pragma unroll
  for (int j = 0; j < 16; ++j){
    float wvv[4];
    float s;
    s = sm2[j];      ld4f(kw2  + (size_t)j * CC + c, wvv);
    kkk4[0]+=s*wvv[0]; kkk4[1]+=s*wvv[1]; kkk4[2]+=s*wvv[2]; kkk4[3]+=s*wvv[3];
    s = sm[64 + j];  ld4f(aw2  + (size_t)j * CC + c, wvv);
    aa4[0]+=s*wvv[0];  aa4[1]+=s*wvv[1];  aa4[2]+=s*wvv[2];  aa4[3]+=s*wvv[3];
    s = sm[80 + j];  ld4f(maw2 + (size_t)j * CC + c, wvv);
    mam4[0]+=s*wvv[0]; mam4[1]+=s*wvv[1]; mam4[2]+=s*wvv[2]; mam4[3]+=s*wvv[3];
    s = sm2[16 + j]; ld4f(mkw2 + (size_t)j * CC + c, wvv);
    mkm4[0]+=s*wvv[0]; mkm4[1]+=s*wvv[1]; mkm4[2]+=s*wvv[2]; mkm4[3]+=s*wvv[3];
  }

  float k0a[4]; ld4bf(K0 + e, k0a);
  float td4[4], taa4[4], tma4[4], tmk4[4];
  ld4f(td + c, td4); ld4f(taa + c, taa4);
  ld4f(tma + c, tma4); ld4f(tmk + c, tmk4);

  float kkv[4];
  float ssq = 0.f;
  #pragma unroll
  for (int i = 0; i < 4; ++i){ kkv[i] = k0a[i] + kkk4[i]; ssq += kkv[i]*kkv[i]; }
  ssq = red16(ssq);
  float rinv = 1.f / fmaxf(sqrtf(ssq), 1e-12f);

  float kkn[4], outb[4], outkf[4], outu[4];
  #pragma unroll
  for (int i = 0; i < 4; ++i){
    float z  = td4[i] + w2a[i];
    float nz = -z;
    float sp = (nz > 15.f) ? nz : log1pf(expf(nz));
    float w  = -sp - 0.5f;               // <= -0.5
    float av = sigm(taa4[i] + aa4[i]);
    float mav = sigm(tma4[i] + mam4[i]);
    float mkv = sigm(tmk4[i] + mkm4[i]);
    kkn[i]  = kkv[i] * rinv;
    outb[i] = -kkn[i] * av;
    outkf[i]= k0a[i] * (mav + av * (1.f - mav)) * expf(w * mkv);
    outu[i] = expf(w);                   // in (0, 0.61]
  }
  st4bf(KKN + e, kkn);
  st4bf(Bb  + e, outb);
  st4bf(K0  + e, outkf);   // in-place: K0 -> KF
  st4bf(UX  + e, outu);
}

// ---------------------------------------------------------------------------
// Recurrence v3: row-parallel, barrier-free, LDS-free.
// 256 blocks = (b, h, rowgroup of 16 rows); 256 threads = 16 rows x 16
// col-groups of 4 columns. All reductions are width-16 wave shuffles.
// 4-stage software pipeline with NAMED registers (compile-time stage index
// -- no dynamically-indexed private arrays, which LLVM demotes to LDS).
// ---------------------------------------------------------------------------
__global__ __launch_bounds__(256) void k_rec(const bf16u* __restrict__ Q,
                                             const bf16u* __restrict__ UX,
                                             const bf16u* __restrict__ KFt,
                                             const bf16u* __restrict__ Vt,
                                             const bf16u* __restrict__ Aa,
                                             const bf16u* __restrict__ Bv,
                                             bf16u* __restrict__ Y){
  const int blk = blockIdx.x;          // 0..255
  const int b   = blk >> 6;
  const int h   = (blk >> 2) & 15;
  const int rg  = blk & 3;
  const int tid = threadIdx.x;
  const int cg  = tid & 15;            // column group (16 lanes, wave-aligned)
  const int i   = rg * 16 + (tid >> 4);// global state row 0..63
  const int j0  = cg * 4;              // first of 4 owned columns
  const size_t base0 = (size_t)(b * TT) * CC + h * HSS;

  float S0 = 0.f, S1 = 0.f, S2 = 0.f, S3 = 0.f;

  ushort4 qA, kA, aA, bA, uA; unsigned short vA;
  ushort4 qB, kB, aB, bB, uB; unsigned short vB;
  ushort4 qC, kC, aC, bC, uC; unsigned short vC;
  ushort4 qD, kD, aD, bD, uD; unsigned short vD;

#define KREC_LOAD(SFX, T_) do{ \
    size_t bn_ = base0 + (size_t)(T_) * CC; \
    q##SFX = *(const ushort4*)(Q   + bn_ + j0); \
    k##SFX = *(const ushort4*)(KFt + bn_ + j0); \
    a##SFX = *(const ushort4*)(Aa  + bn_ + j0); \
    b##SFX = *(const ushort4*)(Bv  + bn_ + j0); \
    u##SFX = *(const ushort4*)(UX  + bn_ + j0); \
    v##SFX = Vt[bn_ + i]; \
  }while(0)

#define KREC_STEP(SFX, T_) do{ \
    float a0 = bf2f(a##SFX.x), a1 = bf2f(a##SFX.y), a2 = bf2f(a##SFX.z), a3 = bf2f(a##SFX.w); \
    float w0 = expf(-bf2f(u##SFX.x)), w1 = expf(-bf2f(u##SFX.y)); \
    float w2 = expf(-bf2f(u##SFX.z)), w3 = expf(-bf2f(u##SFX.w)); \
    float k0 = bf2f(k##SFX.x), k1 = bf2f(k##SFX.y), k2 = bf2f(k##SFX.z), k3 = bf2f(k##SFX.w); \
    float b0 = bf2f(b##SFX.x), b1 = bf2f(b##SFX.y), b2 = bf2f(b##SFX.z), b3 = bf2f(b##SFX.w); \
    float q0 = bf2f(q##SFX.x), q1 = bf2f(q##SFX.y), q2 = bf2f(q##SFX.z), q3 = bf2f(q##SFX.w); \
    float vi = bf2f(v##SFX); \
    float sa = (S0 * a0 + S1 * a1) + (S2 * a2 + S3 * a3); \
    sa += __shfl_xor(sa, 1, 16); sa += __shfl_xor(sa, 2, 16); \
    sa += __shfl_xor(sa, 4, 16); sa += __shfl_xor(sa, 8, 16); \
    S0 = fmaf(S0, w0, fmaf(sa, b0, vi * k0)); \
    S1 = fmaf(S1, w1, fmaf(sa, b1, vi * k1)); \
    S2 = fmaf(S2, w2, fmaf(sa, b2, vi * k2)); \
    S3 = fmaf(S3, w3, fmaf(sa, b3, vi * k3)); \
    float yp = (S0 * q0 + S1 * q1) + (S2 * q2 + S3 * q3); \
    yp += __shfl_xor(yp, 1, 16); yp += __shfl_xor(yp, 2, 16); \
    yp += __shfl_xor(yp, 4, 16); yp += __shfl_xor(yp, 8, 16); \
    if (cg == 0) Y[base0 + (size_t)(T_) * CC + i] = f2bf(yp); \
  }while(0)

  KREC_LOAD(A, 0); KREC_LOAD(B, 1); KREC_LOAD(C, 2); KREC_LOAD(D, 3);
  for (int t = 0; t < TT; t += 4){
    KREC_STEP(A, t);     if (t + 4 < TT) KREC_LOAD(A, t + 4);
    KREC_STEP(B, t + 1); if (t + 5 < TT) KREC_LOAD(B, t + 5);
    KREC_STEP(C, t + 2); if (t + 6 < TT) KREC_LOAD(C, t + 6);
    KREC_STEP(D, t + 3); if (t + 7 < TT) KREC_LOAD(D, t + 7);
  }
#undef KREC_LOAD
#undef KREC_STEP
}

// ---------------------------------------------------------------------------
// Post: GroupNorm + bonus (r.k*faaaa)v + gate -> YG (bf16)
// ---------------------------------------------------------------------------
__global__ __launch_bounds__(256) void k_post(const bf16u* __restrict__ Y,
                                              const bf16u* __restrict__ R,
                                              const bf16u* __restrict__ KFt,
                                              const bf16u* __restrict__ Vt,
                                              const float* __restrict__ GT,
                                              const float* __restrict__ gw2,
                                              const float* __restrict__ lnw,
                                              const float* __restrict__ lnb,
                                              const float* __restrict__ faaaa,
                                              bf16u* __restrict__ YG){
  int n = blockIdx.x, tid = threadIdx.x;
  __shared__ float gt_l[128];
  if (tid < 128) gt_l[tid] = GT[(size_t)n * 128 + tid];
  __syncthreads();
  int c = tid * 4;
  size_t e = (size_t)n * CC + c;

  float ya[4]; ld4bf(Y + e, ya);
  float s = ya[0] + ya[1] + ya[2] + ya[3];
  s = red16(s);
  float mu = s * (1.f / 64.f);
  float d[4], vs = 0.f;
  #pragma unroll
  for (int i = 0; i < 4; ++i){ d[i] = ya[i] - mu; vs += d[i] * d[i]; }
  vs = red16(vs);
  float rstd = rsqrtf(vs * (1.f / 64.f) + EPSGN);

  float r4[4], k4[4], va[4], fa4[4];
  ld4bf(R + e, r4); ld4bf(KFt + e, k4); ld4bf(Vt + e, va);
  ld4f(faaaa + c, fa4);
  float rk = r4[0]*k4[0]*fa4[0] + r4[1]*k4[1]*fa4[1] + r4[2]*k4[2]*fa4[2] + r4[3]*k4[3]*fa4[3];
  rk = red16(rk);

  float lw4[4], lb4[4];
  ld4f(lnw + c, lw4); ld4f(lnb + c, lb4);
  float yn[4];
  #pragma unroll
  for (int i = 0; i < 4; ++i)
    yn[i] = d[i] * rstd * lw4[i] + lb4[i] + rk * va[i];

  float g[4] = {0,0,0,0};
  #pragma unroll 8
  for (int j = 0; j < 128; ++j){
    float gl = gt_l[j];
    float wvv[4]; ld4f(gw2 + (size_t)j * CC + c, wvv);
    g[0] += gl*wvv[0]; g[1] += gl*wvv[1]; g[2] += gl*wvv[2]; g[3] += gl*wvv[3];
  }
  float o[4] = {yn[0]*g[0], yn[1]*g[1], yn[2]*g[2], yn[3]*g[3]};
  st4bf(YG + e, o);
}

// ---------------------------------------------------------------------------
extern "C" void kernel_launch(void* const* d_in, const int* in_sizes, int n_in,
                              void* d_out, int out_size, void* d_ws, size_t ws_size,
                              hipStream_t stream){
  (void)in_sizes; (void)n_in; (void)out_size; (void)ws_size;
  const float* x        = (const float*)d_in[0];
  const float* tmx      = (const float*)d_in[1];
  const float* tmaa     = (const float*)d_in[2];
  const float* maa_w1   = (const float*)d_in[3];
  const float* maa_w2   = (const float*)d_in[4];
  const float* decay_w1 = (const float*)d_in[5];
  const float* decay_w2 = (const float*)d_in[6];
  const float* aaa_w1   = (const float*)d_in[7];
  const float* aaa_w2   = (const float*)d_in[8];
  const float* kkk_w1   = (const float*)d_in[9];
  const float* kkk_w2   = (const float*)d_in[10];
  const float* gate_w1  = (const float*)d_in[11];
  const float* gate_w2  = (const float*)d_in[12];
  const float* ma_w1    = (const float*)d_in[13];
  const float* ma_w2    = (const float*)d_in[14];
  const float* mk_w1    = (const float*)d_in[15];
  const float* mk_w2    = (const float*)d_in[16];
  const float* t_decay  = (const float*)d_in[17];
  const float* t_faaaa  = (const float*)d_in[18];
  const float* t_aaaaa  = (const float*)d_in[19];
  const float* t_misc_a = (const float*)d_in[20];
  const float* t_misc_k = (const float*)d_in[21];
  const float* Wr       = (const float*)d_in[22];
  const float* Wk       = (const float*)d_in[23];
  const float* Wv       = (const float*)d_in[24];
  const float* Wo       = (const float*)d_in[25];
  const float* ln_w     = (const float*)d_in[26];
  const float* ln_b     = (const float*)d_in[27];

  // Layout: 7 bf16 slots of 8MiB + f32 smalls; total 62 MiB.
  // S0: MIX -> X0(xrg) -> KKN -> YG | S1: X1(xwa) -> Bb | S2: X2(xk) -> UX
  // S3: X3(xv) -> Y(bf16) | S4: R | S5: K0 -> KF (in-place) | S6: V
  bf16u* bw  = (bf16u*)d_ws;
  bf16u* MIX = bw + 0*SLOT;
  bf16u* X0  = bw + 0*SLOT;
  bf16u* KKN = bw + 0*SLOT;
  bf16u* YG  = bw + 0*SLOT;
  bf16u* X1  = bw + 1*SLOT;
  bf16u* Bb  = bw + 1*SLOT;
  bf16u* X2  = bw + 2*SLOT;
  bf16u* UX  = bw + 2*SLOT;
  bf16u* X3  = bw + 3*SLOT;
  bf16u* Yb  = bw + 3*SLOT;
  bf16u* R   = bw + 4*SLOT;
  bf16u* K0  = bw + 5*SLOT;   // becomes KF
  bf16u* V   = bw + 6*SLOT;
  char*  wsb = (char*)d_ws;
  float* LO  = (float*)(wsb + (56ull<<20));   // [N,128] f32, 2MiB
  float* GT  = (float*)(wsb + (58ull<<20));   // [N,128] f32, 2MiB
  float* P1  = (float*)(wsb + (60ull<<20));   // [N,96]  f32, 1.5MiB (DT|AT|MA)
  float* P2  = (float*)(wsb + (61ull<<20) + (512ull<<10));  // [N,32] f32, 0.5MiB (KT|MK)

  // 1. mix
  k_prep<<<4096, 256, 0, stream>>>(x, tmx, MIX);
  // 2. lo = tanh(mix @ maa_w1^T)  [N,128]
  k_gemm_mfma<false><<<dim3(1,32),256,0,stream>>>(MIX, maa_w1, maa_w1, maa_w1,
                                                  128, 128, LO, 128, CC, 128);
  // 3. xm[g]
  k_xm<<<4096, 256, 0, stream>>>(x, LO, tmaa, maa_w2, X0, X1, X2, X3);
  // 4. big projections (bf16 out)
  k_gemm_mfma<true><<<dim3(8,32),256,0,stream>>>(X0, Wr, Wr, Wr, CC, CC, R,  CC, CC, 0);
  k_gemm_mfma<true><<<dim3(8,32),256,0,stream>>>(X2, Wk, Wk, Wk, CC, CC, K0, CC, CC, 0);
  k_gemm_mfma<true><<<dim3(8,32),256,0,stream>>>(X3, Wv, Wv, Wv, CC, CC, V,  CC, CC, 0);
  // 5. small first-stage projections (fused, f32 out)
  k_gemm_mfma<false><<<dim3(1,32),256,0,stream>>>(X0, gate_w1, gate_w1, gate_w1,
                                                  128, 128, GT, 128, CC, 128);
  k_gemm_mfma<false><<<dim3(1,32),256,0,stream>>>(X1, decay_w1, aaa_w1, ma_w1,
                                                  64, 80, P1, 96, CC, 64);
  k_gemm_mfma<false><<<dim3(1,32),256,0,stream>>>(X2, kkk_w1, mk_w1, mk_w1,
                                                  16, 32, P2, 32, CC, 16);
  // 6. fused elementwise
  k_elem<<<4096, 256, 0, stream>>>(K0, P1, P2,
                                   decay_w2, kkk_w2, aaa_w2, ma_w2, mk_w2,
                                   t_decay, t_aaaaa, t_misc_a, t_misc_k,
                                   KKN, Bb, UX);
  // 7. delta-rule recurrence (row-parallel, 256 blocks, barrier/LDS-free)
  k_rec<<<256, 256, 0, stream>>>(R, UX, K0, V, KKN, Bb, Yb);
  // 8. groupnorm + bonus + gate
  k_post<<<4096, 256, 0, stream>>>(Yb, R, K0, V, GT, gate_w2, ln_w, ln_b, t_faaaa, YG);
  // 9. out = yg @ Wo^T  -> f32 output
  k_gemm_mfma<false><<<dim3(8,32),256,0,stream>>>(YG, Wo, Wo, Wo, CC, CC, d_out, CC, CC, 0);
}

// Round 8
// 1036.336 us; speedup vs baseline: 3.2323x; 1.2275x over previous
//
#include <hip/hip_runtime.h>
#include <cstdint>
#include <cstddef>

// Problem constants
#define BB   4
#define TT   1024
#define CC   1024
#define HH   16
#define HSS  64
#define NNtok 4096            // B*T
#define EPSGN 0.00064f

typedef unsigned short bf16u;
typedef __attribute__((ext_vector_type(8))) short short8;
typedef __attribute__((ext_vector_type(4))) float f32x4;
#define SLOT 4194304ull       // elements per 8MiB bf16 slot (= NNtok*CC)

__device__ __forceinline__ float bf2f(bf16u u){
  union { unsigned int i; float f; } cv; cv.i = ((unsigned int)u) << 16; return cv.f;
}
__device__ __forceinline__ unsigned short f2bfbits(unsigned int x){
  return (unsigned short)((x + 0x7fffu + ((x >> 16) & 1u)) >> 16);   // RNE
}
__device__ __forceinline__ bf16u f2bf(float f){
  union { float f; unsigned int i; } cv; cv.f = f;
  return f2bfbits(cv.i);
}
__device__ __forceinline__ void ld4bf(const bf16u* p, float* o){
  ushort4 u = *reinterpret_cast<const ushort4*>(p);
  o[0]=bf2f(u.x); o[1]=bf2f(u.y); o[2]=bf2f(u.z); o[3]=bf2f(u.w);
}
__device__ __forceinline__ void st4bf(bf16u* p, const float* v){
  ushort4 u; u.x=f2bf(v[0]); u.y=f2bf(v[1]); u.z=f2bf(v[2]); u.w=f2bf(v[3]);
  *reinterpret_cast<ushort4*>(p) = u;
}
__device__ __forceinline__ void ld4f(const float* p, float* o){
  float4 v = *reinterpret_cast<const float4*>(p);
  o[0]=v.x; o[1]=v.y; o[2]=v.z; o[3]=v.w;
}
__device__ __forceinline__ float sigm(float x){ return 1.f / (1.f + expf(-x)); }
__device__ __forceinline__ float red16(float v){
  v += __shfl_xor(v, 1, 16); v += __shfl_xor(v, 2, 16);
  v += __shfl_xor(v, 4, 16); v += __shfl_xor(v, 8, 16);
  return v;
}

// ---------------------------------------------------------------------------
// mix = x + (x[t-1]-x[t])*time_maa_x  (x[-1]=0), stored bf16
// ---------------------------------------------------------------------------
__global__ __launch_bounds__(256) void k_prep(const float* __restrict__ x,
                                              const float* __restrict__ tmx,
                                              bf16u* __restrict__ MIX){
  int e = (blockIdx.x * 256 + threadIdx.x) * 4;
  int n = e >> 10;
  int c = e & (CC - 1);
  int t = n & (TT - 1);
  float xf[4]; ld4f(x + e, xf);
  float pf[4] = {0.f, 0.f, 0.f, 0.f};
  if (t > 0) ld4f(x + e - CC, pf);
  float tm[4]; ld4f(tmx + c, tm);
  float mv[4];
  #pragma unroll
  for (int i = 0; i < 4; ++i) mv[i] = xf[i] + (pf[i] - xf[i]) * tm[i];
  st4bf(MIX + e, mv);
}

// ---------------------------------------------------------------------------
// MFMA NT GEMM: OUT[M,Nd] = X[M,K](bf16) @ W[Nd,K]^T, W as up to 3 row-blocks
// (f32). tanh on cols < act_n. OB: bf16 out else f32. 128x128, BK=32.
// ---------------------------------------------------------------------------
template<bool OB>
__global__ __launch_bounds__(256) void k_gemm_mfma(const bf16u* __restrict__ X,
                                                   const float* __restrict__ Wa,
                                                   const float* __restrict__ Wb,
                                                   const float* __restrict__ Wc,
                                                   int na, int nab,
                                                   void* __restrict__ OUTv,
                                                   int Nd, int Kd, int act_n){
  __shared__ short As[128 * 40];
  __shared__ short Bs[128 * 40];
  const int tid  = threadIdx.x;
  const int lane = tid & 63;
  const int wv   = tid >> 6;
  const int wm   = wv >> 1, wn = wv & 1;
  const int bn0  = blockIdx.x * 128;
  const int bm0  = blockIdx.y * 128;
  const int l15  = lane & 15;
  const int quad = lane >> 4;

  f32x4 acc[4][4];
  #pragma unroll
  for (int mi = 0; mi < 4; ++mi)
    #pragma unroll
    for (int ni = 0; ni < 4; ++ni)
      #pragma unroll
      for (int rg = 0; rg < 4; ++rg) acc[mi][ni][rg] = 0.f;

  const int r    = tid >> 1;
  const int half = (tid & 1) * 16;

  int rr = bn0 + r;
  const float* wsrc = nullptr;
  if (rr < na)        wsrc = Wa + (size_t)rr * Kd;
  else if (rr < nab)  wsrc = Wb + (size_t)(rr - na) * Kd;
  else if (rr < Nd)   wsrc = Wc + (size_t)(rr - nab) * Kd;
  const bf16u* xsrc = X + (size_t)(bm0 + r) * Kd;

  for (int k0 = 0; k0 < Kd; k0 += 32){
    uint4 xa = *(const uint4*)(xsrc + k0 + half);
    uint4 xb = *(const uint4*)(xsrc + k0 + half + 8);
    uint4 w0 = make_uint4(0,0,0,0), w1 = w0, w2 = w0, w3 = w0;
    if (wsrc){
      w0 = *(const uint4*)(wsrc + k0 + half);
      w1 = *(const uint4*)(wsrc + k0 + half + 4);
      w2 = *(const uint4*)(wsrc + k0 + half + 8);
      w3 = *(const uint4*)(wsrc + k0 + half + 12);
    }
    union { unsigned short s[8]; uint4 v; } p0, p1;
    p0.s[0]=f2bfbits(w0.x); p0.s[1]=f2bfbits(w0.y); p0.s[2]=f2bfbits(w0.z); p0.s[3]=f2bfbits(w0.w);
    p0.s[4]=f2bfbits(w1.x); p0.s[5]=f2bfbits(w1.y); p0.s[6]=f2bfbits(w1.z); p0.s[7]=f2bfbits(w1.w);
    p1.s[0]=f2bfbits(w2.x); p1.s[1]=f2bfbits(w2.y); p1.s[2]=f2bfbits(w2.z); p1.s[3]=f2bfbits(w2.w);
    p1.s[4]=f2bfbits(w3.x); p1.s[5]=f2bfbits(w3.y); p1.s[6]=f2bfbits(w3.z); p1.s[7]=f2bfbits(w3.w);

    *(uint4*)&As[r * 40 + half]     = xa;
    *(uint4*)&As[r * 40 + half + 8] = xb;
    *(uint4*)&Bs[r * 40 + half]     = p0.v;
    *(uint4*)&Bs[r * 40 + half + 8] = p1.v;
    __syncthreads();

    short8 af[4], bfg[4];
    #pragma unroll
    for (int mi = 0; mi < 4; ++mi)
      af[mi] = *(const short8*)&As[(wm*64 + mi*16 + l15) * 40 + quad*8];
    #pragma unroll
    for (int ni = 0; ni < 4; ++ni)
      bfg[ni] = *(const short8*)&Bs[(wn*64 + ni*16 + l15) * 40 + quad*8];
    #pragma unroll
    for (int mi = 0; mi < 4; ++mi)
      #pragma unroll
      for (int ni = 0; ni < 4; ++ni)
        acc[mi][ni] = __builtin_amdgcn_mfma_f32_16x16x32_bf16(af[mi], bfg[ni], acc[mi][ni], 0, 0, 0);
    __syncthreads();
  }

  #pragma unroll
  for (int mi = 0; mi < 4; ++mi){
    #pragma unroll
    for (int ni = 0; ni < 4; ++ni){
      int col = bn0 + wn*64 + ni*16 + l15;
      if (col >= Nd) continue;
      #pragma unroll
      for (int rg = 0; rg < 4; ++rg){
        int row = bm0 + wm*64 + mi*16 + quad*4 + rg;
        float v = acc[mi][ni][rg];
        if (col < act_n) v = tanhf(v);
        if (OB) ((bf16u*)OUTv)[(size_t)row * Nd + col] = f2bf(v);
        else    ((float*)OUTv)[(size_t)row * Nd + col] = v;
      }
    }
  }
}

// ---------------------------------------------------------------------------
// MFMA NN GEMM: OUT[M, CC] = A[M, KD](bf16, row stride lda) @ B[KD, CC](f32).
// EP=0: plain bf16 store. EP=1: token-shift epilogue
//   OUT = x + (x[prev]-x)*(acc + tma_g[col])   (prev=0 at seq start)
// 128x128 tile, single staged K (KD <= 128).
// ---------------------------------------------------------------------------
template<int KD, int EP>
__global__ __launch_bounds__(256) void k_gemm_nn(const bf16u* __restrict__ A, int lda,
                                                 const float* __restrict__ B,
                                                 bf16u* __restrict__ OUT,
                                                 const float* __restrict__ x,
                                                 const float* __restrict__ tma_g){
  __shared__ short As[128 * (KD + 8)];
  __shared__ short Bs[128 * (KD + 8)];
  const int tid  = threadIdx.x;
  const int lane = tid & 63;
  const int wv   = tid >> 6;
  const int wm   = wv >> 1, wn = wv & 1;
  const int bn0  = blockIdx.x * 128;
  const int bm0  = blockIdx.y * 128;
  const int l15  = lane & 15;
  const int quad = lane >> 4;

  // stage A rows (bf16, vectorized)
  for (int idx = tid; idx < 128 * (KD / 8); idx += 256){
    int r  = idx / (KD / 8);
    int kc = (idx % (KD / 8)) * 8;
    *(uint4*)&As[r * (KD + 8) + kc] =
        *(const uint4*)(A + (size_t)(bm0 + r) * lda + kc);
  }
  // stage B transposed: Bs[c][k] = bf16(B[k][bn0+c])
  for (int idx = tid; idx < KD * 128; idx += 256){
    int k = idx >> 7, c = idx & 127;
    Bs[c * (KD + 8) + k] = (short)f2bf(B[(size_t)k * CC + bn0 + c]);
  }
  __syncthreads();

  f32x4 acc[4][4];
  #pragma unroll
  for (int mi = 0; mi < 4; ++mi)
    #pragma unroll
    for (int ni = 0; ni < 4; ++ni)
      #pragma unroll
      for (int rg = 0; rg < 4; ++rg) acc[mi][ni][rg] = 0.f;

  #pragma unroll
  for (int kk = 0; kk < KD; kk += 32){
    short8 af[4], bfg[4];
    #pragma unroll
    for (int mi = 0; mi < 4; ++mi)
      af[mi] = *(const short8*)&As[(wm*64 + mi*16 + l15) * (KD + 8) + kk + quad*8];
    #pragma unroll
    for (int ni = 0; ni < 4; ++ni)
      bfg[ni] = *(const short8*)&Bs[(wn*64 + ni*16 + l15) * (KD + 8) + kk + quad*8];
    #pragma unroll
    for (int mi = 0; mi < 4; ++mi)
      #pragma unroll
      for (int ni = 0; ni < 4; ++ni)
        acc[mi][ni] = __builtin_amdgcn_mfma_f32_16x16x32_bf16(af[mi], bfg[ni], acc[mi][ni], 0, 0, 0);
  }

  #pragma unroll
  for (int mi = 0; mi < 4; ++mi){
    #pragma unroll
    for (int ni = 0; ni < 4; ++ni){
      int col = bn0 + wn*64 + ni*16 + l15;
      float tm = (EP == 1) ? tma_g[col] : 0.f;
      #pragma unroll
      for (int rg = 0; rg < 4; ++rg){
        int row = bm0 + wm*64 + mi*16 + quad*4 + rg;
        float v = acc[mi][ni][rg];
        if (EP == 1){
          float xv = x[(size_t)row * CC + col];
          float xp = ((row & (TT - 1)) == 0) ? 0.f : x[(size_t)row * CC + col - CC];
          v = xv + (xp - xv) * (v + tm);
        }
        OUT[(size_t)row * CC + col] = f2bf(v);
      }
    }
  }
}

// ---------------------------------------------------------------------------
// Fused elementwise, tiled 4 tokens/block. Rank-16 LoRA second matmuls with
// 4x weight reuse; decay projection comes precomputed (W2A, via GEMM).
// Outputs: KF (in-place over K0), KKN, Bb, UX = exp(w)  (bf16)
// ---------------------------------------------------------------------------
__global__ __launch_bounds__(256) void k_elem(bf16u* __restrict__ K0,
    const bf16u* __restrict__ P1, const bf16u* __restrict__ P2,
    const bf16u* __restrict__ W2A,
    const float* __restrict__ kw2, const float* __restrict__ aw2,
    const float* __restrict__ maw2, const float* __restrict__ mkw2,
    const float* __restrict__ td,  const float* __restrict__ taa,
    const float* __restrict__ tma, const float* __restrict__ tmk,
    bf16u* __restrict__ KKN, bf16u* __restrict__ Bb, bf16u* __restrict__ UX){
  int n0 = blockIdx.x * 4, tid = threadIdx.x;
  __shared__ float at_l[4][16], mat_l[4][16], kt_l[4][16], mkt_l[4][16];
  {
    int grp = tid >> 6, q = tid & 63, tt = q >> 4, j = q & 15;
    if (grp == 0)      at_l[tt][j]  = bf2f(P1[(size_t)(n0+tt)*96 + 64 + j]);
    else if (grp == 1) mat_l[tt][j] = bf2f(P1[(size_t)(n0+tt)*96 + 80 + j]);
    else if (grp == 2) kt_l[tt][j]  = bf2f(P2[(size_t)(n0+tt)*32 + j]);
    else               mkt_l[tt][j] = bf2f(P2[(size_t)(n0+tt)*32 + 16 + j]);
  }
  __syncthreads();
  int c = tid * 4;

  float kkk[4][4], aa[4][4], mam[4][4], mkm[4][4];
  #pragma unroll
  for (int tt = 0; tt < 4; ++tt)
    #pragma unroll
    for (int i = 0; i < 4; ++i){ kkk[tt][i]=0; aa[tt][i]=0; mam[tt][i]=0; mkm[tt][i]=0; }

  #pragma unroll 4
  for (int j = 0; j < 16; ++j){
    float wk[4], wa[4], wm[4], wq[4];
    ld4f(kw2  + (size_t)j*CC + c, wk);
    ld4f(aw2  + (size_t)j*CC + c, wa);
    ld4f(maw2 + (size_t)j*CC + c, wm);
    ld4f(mkw2 + (size_t)j*CC + c, wq);
    #pragma unroll
    for (int tt = 0; tt < 4; ++tt){
      float s1 = kt_l[tt][j], s2 = at_l[tt][j], s3 = mat_l[tt][j], s4 = mkt_l[tt][j];
      #pragma unroll
      for (int i = 0; i < 4; ++i){
        kkk[tt][i] += s1 * wk[i];
        aa[tt][i]  += s2 * wa[i];
        mam[tt][i] += s3 * wm[i];
        mkm[tt][i] += s4 * wq[i];
      }
    }
  }

  float td4[4], taa4[4], tma4[4], tmk4[4];
  ld4f(td + c, td4); ld4f(taa + c, taa4); ld4f(tma + c, tma4); ld4f(tmk + c, tmk4);

  for (int tt = 0; tt < 4; ++tt){
    size_t e = (size_t)(n0 + tt) * CC + c;
    float k0a[4]; ld4bf(K0 + e, k0a);
    float w2a[4]; ld4bf(W2A + e, w2a);

    float kkv[4];
    float ssq = 0.f;
    #pragma unroll
    for (int i = 0; i < 4; ++i){ kkv[i] = k0a[i] + kkk[tt][i]; ssq += kkv[i]*kkv[i]; }
    ssq = red16(ssq);
    float rinv = 1.f / fmaxf(sqrtf(ssq), 1e-12f);

    float kkn[4], outb[4], outkf[4], outu[4];
    #pragma unroll
    for (int i = 0; i < 4; ++i){
      float z  = td4[i] + w2a[i];
      float nz = -z;
      float sp = (nz > 15.f) ? nz : log1pf(expf(nz));
      float w  = -sp - 0.5f;               // <= -0.5
      float av  = sigm(taa4[i] + aa[tt][i]);
      float mav = sigm(tma4[i] + mam[tt][i]);
      float mkv = sigm(tmk4[i] + mkm[tt][i]);
      kkn[i]  = kkv[i] * rinv;
      outb[i] = -kkn[i] * av;
      outkf[i]= k0a[i] * (mav + av * (1.f - mav)) * expf(w * mkv);
      outu[i] = expf(w);                   // in (0, 0.61]
    }
    st4bf(KKN + e, kkn);
    st4bf(Bb  + e, outb);
    st4bf(K0  + e, outkf);
    st4bf(UX  + e, outu);
  }
}

// ---------------------------------------------------------------------------
// Recurrence v4: row-parallel, barrier/LDS-free, native exp, deferred-yp.
// 256 blocks = (b,h,rowgroup16); thread = (row, 4 cols). yp of step t is
// shuffle-reduced during step t+1 (off the serial chain).
// ---------------------------------------------------------------------------
__global__ __launch_bounds__(256) void k_rec(const bf16u* __restrict__ Q,
                                             const bf16u* __restrict__ UX,
                                             const bf16u* __restrict__ KFt,
                                             const bf16u* __restrict__ Vt,
                                             const bf16u* __restrict__ Aa,
                                             const bf16u* __restrict__ Bv,
                                             bf16u* __restrict__ Y){
  const int blk = blockIdx.x;          // 0..255
  const int b   = blk >> 6;
  const int h   = (blk >> 2) & 15;
  const int rg  = blk & 3;
  const int tid = threadIdx.x;
  const int cg  = tid & 15;
  const int i   = rg * 16 + (tid >> 4);
  const int j0  = cg * 4;
  const size_t base0 = (size_t)(b * TT) * CC + h * HSS;

  float S0 = 0.f, S1 = 0.f, S2 = 0.f, S3 = 0.f;
  float ypA = 0.f, ypB = 0.f, ypC = 0.f, ypD = 0.f;

  ushort4 qA, kA, aA, bA, uA; unsigned short vA;
  ushort4 qB, kB, aB, bB, uB; unsigned short vB;
  ushort4 qC, kC, aC, bC, uC; unsigned short vC;
  ushort4 qD, kD, aD, bD, uD; unsigned short vD;

#define KREC_LOAD(SFX, T_) do{ \
    size_t bn_ = base0 + (size_t)(T_) * CC; \
    q##SFX = *(const ushort4*)(Q   + bn_ + j0); \
    k##SFX = *(const ushort4*)(KFt + bn_ + j0); \
    a##SFX = *(const ushort4*)(Aa  + bn_ + j0); \
    b##SFX = *(const ushort4*)(Bv  + bn_ + j0); \
    u##SFX = *(const ushort4*)(UX  + bn_ + j0); \
    v##SFX = Vt[bn_ + i]; \
  }while(0)

#define KREC_STEP(SFX) do{ \
    float a0 = bf2f(a##SFX.x), a1 = bf2f(a##SFX.y), a2 = bf2f(a##SFX.z), a3 = bf2f(a##SFX.w); \
    float w0 = __expf(-bf2f(u##SFX.x)), w1 = __expf(-bf2f(u##SFX.y)); \
    float w2 = __expf(-bf2f(u##SFX.z)), w3 = __expf(-bf2f(u##SFX.w)); \
    float k0 = bf2f(k##SFX.x), k1 = bf2f(k##SFX.y), k2 = bf2f(k##SFX.z), k3 = bf2f(k##SFX.w); \
    float b0 = bf2f(b##SFX.x), b1 = bf2f(b##SFX.y), b2 = bf2f(b##SFX.z), b3 = bf2f(b##SFX.w); \
    float q0 = bf2f(q##SFX.x), q1 = bf2f(q##SFX.y), q2 = bf2f(q##SFX.z), q3 = bf2f(q##SFX.w); \
    float vi = bf2f(v##SFX); \
    float sa = (S0 * a0 + S1 * a1) + (S2 * a2 + S3 * a3); \
    sa += __shfl_xor(sa, 1, 16); sa += __shfl_xor(sa, 2, 16); \
    sa += __shfl_xor(sa, 4, 16); sa += __shfl_xor(sa, 8, 16); \
    S0 = fmaf(S0, w0, fmaf(sa, b0, vi * k0)); \
    S1 = fmaf(S1, w1, fmaf(sa, b1, vi * k1)); \
    S2 = fmaf(S2, w2, fmaf(sa, b2, vi * k2)); \
    S3 = fmaf(S3, w3, fmaf(sa, b3, vi * k3)); \
    yp##SFX = (S0 * q0 + S1 * q1) + (S2 * q2 + S3 * q3); \
  }while(0)

#define KREC_FLUSH(SFX, T_) do{ \
    float yp_ = yp##SFX; \
    yp_ += __shfl_xor(yp_, 1, 16); yp_ += __shfl_xor(yp_, 2, 16); \
    yp_ += __shfl_xor(yp_, 4, 16); yp_ += __shfl_xor(yp_, 8, 16); \
    if (cg == 0) Y[base0 + (size_t)(T_) * CC + i] = f2bf(yp_); \
  }while(0)

  KREC_LOAD(A, 0); KREC_LOAD(B, 1); KREC_LOAD(C, 2); KREC_LOAD(D, 3);
  for (int t = 0; t < TT; t += 4){
    KREC_STEP(A);
    if (t) KREC_FLUSH(D, t - 1);
    if (t + 4 < TT) KREC_LOAD(A, t + 4);
    KREC_STEP(B);
    KREC_FLUSH(A, t);
    if (t + 5 < TT) KREC_LOAD(B, t + 5);
    KREC_STEP(C);
    KREC_FLUSH(B, t + 1);
    if (t + 6 < TT) KREC_LOAD(C, t + 6);
    KREC_STEP(D);
    KREC_FLUSH(C, t + 2);
    if (t + 7 < TT) KREC_LOAD(D, t + 7);
  }
  KREC_FLUSH(D, TT - 1);
#undef KREC_LOAD
#undef KREC_STEP
#undef KREC_FLUSH
}

// ---------------------------------------------------------------------------
// Post: GroupNorm + bonus (r.k*faaaa)v + precomputed gate GV -> YG (bf16)
// Pure streaming now (no weight loops).
// ---------------------------------------------------------------------------
__global__ __launch_bounds__(256) void k_post(const bf16u* __restrict__ Y,
                                              const bf16u* __restrict__ R,
                                              const bf16u* __restrict__ KFt,
                                              const bf16u* __restrict__ Vt,
                                              const bf16u* __restrict__ GV,
                                              const float* __restrict__ lnw,
                                              const float* __restrict__ lnb,
                                              const float* __restrict__ faaaa,
                                              bf16u* __restrict__ YG){
  int n = blockIdx.x, tid = threadIdx.x;
  int c = tid * 4;
  size_t e = (size_t)n * CC + c;

  float ya[4]; ld4bf(Y + e, ya);
  float s = ya[0] + ya[1] + ya[2] + ya[3];
  s = red16(s);
  float mu = s * (1.f / 64.f);
  float d[4], vs = 0.f;
  #pragma unroll
  for (int i = 0; i < 4; ++i){ d[i] = ya[i] - mu; vs += d[i] * d[i]; }
  vs = red16(vs);
  float rstd = rsqrtf(vs * (1.f / 64.f) + EPSGN);

  float r4[4], k4[4], va[4], fa4[4];
  ld4bf(R + e, r4); ld4bf(KFt + e, k4); ld4bf(Vt + e, va);
  ld4f(faaaa + c, fa4);
  float rk = r4[0]*k4[0]*fa4[0] + r4[1]*k4[1]*fa4[1] + r4[2]*k4[2]*fa4[2] + r4[3]*k4[3]*fa4[3];
  rk = red16(rk);

  float lw4[4], lb4[4];
  ld4f(lnw + c, lw4); ld4f(lnb + c, lb4);
  float g[4]; ld4bf(GV + e, g);
  float o[4];
  #pragma unroll
  for (int i = 0; i < 4; ++i){
    float yn = d[i] * rstd * lw4[i] + lb4[i] + rk * va[i];
    o[i] = yn * g[i];
  }
  st4bf(YG + e, o);
}

// ---------------------------------------------------------------------------
extern "C" void kernel_launch(void* const* d_in, const int* in_sizes, int n_in,
                              void* d_out, int out_size, void* d_ws, size_t ws_size,
                              hipStream_t stream){
  (void)in_sizes; (void)n_in; (void)out_size; (void)ws_size;
  const float* x        = (const float*)d_in[0];
  const float* tmx      = (const float*)d_in[1];
  const float* tmaa     = (const float*)d_in[2];
  const float* maa_w1   = (const float*)d_in[3];
  const float* maa_w2   = (const float*)d_in[4];
  const float* decay_w1 = (const float*)d_in[5];
  const float* decay_w2 = (const float*)d_in[6];
  const float* aaa_w1   = (const float*)d_in[7];
  const float* aaa_w2   = (const float*)d_in[8];
  const float* kkk_w1   = (const float*)d_in[9];
  const float* kkk_w2   = (const float*)d_in[10];
  const float* gate_w1  = (const float*)d_in[11];
  const float* gate_w2  = (const float*)d_in[12];
  const float* ma_w1    = (const float*)d_in[13];
  const float* ma_w2    = (const float*)d_in[14];
  const float* mk_w1    = (const float*)d_in[15];
  const float* mk_w2    = (const float*)d_in[16];
  const float* t_decay  = (const float*)d_in[17];
  const float* t_faaaa  = (const float*)d_in[18];
  const float* t_aaaaa  = (const float*)d_in[19];
  const float* t_misc_a = (const float*)d_in[20];
  const float* t_misc_k = (const float*)d_in[21];
  const float* Wr       = (const float*)d_in[22];
  const float* Wk       = (const float*)d_in[23];
  const float* Wv       = (const float*)d_in[24];
  const float* Wo       = (const float*)d_in[25];
  const float* ln_w     = (const float*)d_in[26];
  const float* ln_b     = (const float*)d_in[27];

  // Slot map (8MiB bf16 each), 56 MiB + ~3 MiB smalls:
  // S0: MIX -> X0 -> KKN -> YG | S1: X1 -> Bb -> GV | S2: X2 -> UX
  // S3: X3 -> W2A -> Yb | S4: R | S5: K0 -> KF | S6: V
  bf16u* bw  = (bf16u*)d_ws;
  bf16u* MIX = bw + 0*SLOT;
  bf16u* X0  = bw + 0*SLOT;
  bf16u* KKN = bw + 0*SLOT;
  bf16u* YG  = bw + 0*SLOT;
  bf16u* X1  = bw + 1*SLOT;
  bf16u* Bb  = bw + 1*SLOT;
  bf16u* GV  = bw + 1*SLOT;
  bf16u* X2  = bw + 2*SLOT;
  bf16u* UX  = bw + 2*SLOT;
  bf16u* X3  = bw + 3*SLOT;
  bf16u* W2A = bw + 3*SLOT;
  bf16u* Yb  = bw + 3*SLOT;
  bf16u* R   = bw + 4*SLOT;
  bf16u* K0  = bw + 5*SLOT;   // becomes KF
  bf16u* V   = bw + 6*SLOT;
  char*  wsb = (char*)d_ws;
  bf16u* LO  = (bf16u*)(wsb + (56ull<<20));   // [N,128] bf16, 1 MiB
  bf16u* GT  = (bf16u*)(wsb + (57ull<<20));   // [N,128] bf16, 1 MiB
  bf16u* P1  = (bf16u*)(wsb + (58ull<<20));   // [N,96]  bf16 (dt|at|ma), .75 MiB
  bf16u* P2  = (bf16u*)(wsb + (58ull<<20) + (768ull<<10)); // [N,32] bf16, .25 MiB

  // 1. mix
  k_prep<<<4096, 256, 0, stream>>>(x, tmx, MIX);
  // 2. lo = tanh(mix @ maa_w1^T) [N,128] bf16
  k_gemm_mfma<true><<<dim3(1,32),256,0,stream>>>(MIX, maa_w1, maa_w1, maa_w1,
                                                 128, 128, LO, 128, CC, 128);
  // 3. xm[g] = x + xx*(lo_g @ maa_w2_g + tmaa_g)   (NN GEMM + fused epilogue)
  bf16u* XMs[4] = {X0, X1, X2, X3};
  for (int g = 0; g < 4; ++g)
    k_gemm_nn<32,1><<<dim3(8,32),256,0,stream>>>(LO + g*32, 128,
                                                 maa_w2 + (size_t)g*32*CC,
                                                 XMs[g], x, tmaa + (size_t)g*CC);
  // 4. big projections (bf16 out)
  k_gemm_mfma<true><<<dim3(8,32),256,0,stream>>>(X0, Wr, Wr, Wr, CC, CC, R,  CC, CC, 0);
  k_gemm_mfma<true><<<dim3(8,32),256,0,stream>>>(X2, Wk, Wk, Wk, CC, CC, K0, CC, CC, 0);
  k_gemm_mfma<true><<<dim3(8,32),256,0,stream>>>(X3, Wv, Wv, Wv, CC, CC, V,  CC, CC, 0);
  // 5. first-stage LoRA projections (bf16 out)
  k_gemm_mfma<true><<<dim3(1,32),256,0,stream>>>(X0, gate_w1, gate_w1, gate_w1,
                                                 128, 128, GT, 128, CC, 128);
  k_gemm_mfma<true><<<dim3(1,32),256,0,stream>>>(X1, decay_w1, aaa_w1, ma_w1,
                                                 64, 80, P1, 96, CC, 64);
  k_gemm_mfma<true><<<dim3(1,32),256,0,stream>>>(X2, kkk_w1, mk_w1, mk_w1,
                                                 16, 32, P2, 32, CC, 16);
  // 6. decay second-stage projection: W2A = P1[:, :64] @ decay_w2  -> S3
  k_gemm_nn<64,0><<<dim3(8,32),256,0,stream>>>(P1, 96, decay_w2, W2A, nullptr, nullptr);
  // 7. fused elementwise (4 tokens/block)
  k_elem<<<1024, 256, 0, stream>>>(K0, P1, P2, W2A,
                                   kkk_w2, aaa_w2, ma_w2, mk_w2,
                                   t_decay, t_aaaaa, t_misc_a, t_misc_k,
                                   KKN, Bb, UX);
  // 8. delta-rule recurrence
  k_rec<<<256, 256, 0, stream>>>(R, UX, K0, V, KKN, Bb, Yb);
  // 9. gate second-stage: GV = GT @ gate_w2 -> S1 (Bb dead after k_rec)
  k_gemm_nn<128,0><<<dim3(8,32),256,0,stream>>>(GT, 128, gate_w2, GV, nullptr, nullptr);
  // 10. groupnorm + bonus + gate
  k_post<<<4096, 256, 0, stream>>>(Yb, R, K0, V, GV, ln_w, ln_b, t_faaaa, YG);
  // 11. out = yg @ Wo^T -> f32
  k_gemm_mfma<false><<<dim3(8,32),256,0,stream>>>(YG, Wo, Wo, Wo, CC, CC, d_out, CC, CC, 0);
}

// Round 9
// 944.721 us; speedup vs baseline: 3.5457x; 1.0970x over previous
//
#include <hip/hip_runtime.h>
#include <cstdint>
#include <cstddef>

// Problem constants
#define BB   4
#define TT   1024
#define CC   1024
#define HH   16
#define HSS  64
#define NNtok 4096            // B*T
#define EPSGN 0.00064f

typedef unsigned short bf16u;
typedef __attribute__((ext_vector_type(8))) short short8;
typedef __attribute__((ext_vector_type(4))) float f32x4;
#define SLOT 4194304ull       // elements per 8MiB bf16 slot (= NNtok*CC)

__device__ __forceinline__ float bf2f(bf16u u){
  union { unsigned int i; float f; } cv; cv.i = ((unsigned int)u) << 16; return cv.f;
}
__device__ __forceinline__ unsigned short f2bfbits(unsigned int x){
  return (unsigned short)((x + 0x7fffu + ((x >> 16) & 1u)) >> 16);   // RNE
}
__device__ __forceinline__ bf16u f2bf(float f){
  union { float f; unsigned int i; } cv; cv.f = f;
  return f2bfbits(cv.i);
}
__device__ __forceinline__ void ld4bf(const bf16u* p, float* o){
  ushort4 u = *reinterpret_cast<const ushort4*>(p);
  o[0]=bf2f(u.x); o[1]=bf2f(u.y); o[2]=bf2f(u.z); o[3]=bf2f(u.w);
}
__device__ __forceinline__ void st4bf(bf16u* p, const float* v){
  ushort4 u; u.x=f2bf(v[0]); u.y=f2bf(v[1]); u.z=f2bf(v[2]); u.w=f2bf(v[3]);
  *reinterpret_cast<ushort4*>(p) = u;
}
__device__ __forceinline__ void ld4f(const float* p, float* o){
  float4 v = *reinterpret_cast<const float4*>(p);
  o[0]=v.x; o[1]=v.y; o[2]=v.z; o[3]=v.w;
}
__device__ __forceinline__ float sigm(float x){ return 1.f / (1.f + expf(-x)); }

// 16-lane sum via DPP (groups must be 16-lane aligned). 4 plain-VALU adds,
// no ds_bpermute / lgkmcnt waits on the critical path.
template<int CTRL>
__device__ __forceinline__ float dpp_add(float v){
  union { float f; int i; } a, b;
  a.f = v;
  b.i = __builtin_amdgcn_update_dpp(a.i, a.i, CTRL, 0xF, 0xF, false);
  return v + b.f;
}
__device__ __forceinline__ float red16(float v){
  v = dpp_add<0xB1>(v);    // quad_perm [1,0,3,2]  (xor 1)
  v = dpp_add<0x4E>(v);    // quad_perm [2,3,0,1]  (xor 2)
  v = dpp_add<0x124>(v);   // row_ror:4
  v = dpp_add<0x128>(v);   // row_ror:8
  return v;
}

// ---------------------------------------------------------------------------
// mix = x + (x[t-1]-x[t])*time_maa_x  (x[-1]=0), stored bf16
// ---------------------------------------------------------------------------
__global__ __launch_bounds__(256) void k_prep(const float* __restrict__ x,
                                              const float* __restrict__ tmx,
                                              bf16u* __restrict__ MIX){
  int e = (blockIdx.x * 256 + threadIdx.x) * 4;
  int n = e >> 10;
  int c = e & (CC - 1);
  int t = n & (TT - 1);
  float xf[4]; ld4f(x + e, xf);
  float pf[4] = {0.f, 0.f, 0.f, 0.f};
  if (t > 0) ld4f(x + e - CC, pf);
  float tm[4]; ld4f(tmx + c, tm);
  float mv[4];
  #pragma unroll
  for (int i = 0; i < 4; ++i) mv[i] = xf[i] + (pf[i] - xf[i]) * tm[i];
  st4bf(MIX + e, mv);
}

// ---------------------------------------------------------------------------
// MFMA NT GEMM: OUT[M,Nd] = X[M,K](bf16) @ W[Nd,K]^T, W as up to 3 row-blocks
// (f32). tanh on cols < act_n. OB: bf16 out else f32. 128x128, BK=32.
// ---------------------------------------------------------------------------
template<bool OB>
__global__ __launch_bounds__(256) void k_gemm_mfma(const bf16u* __restrict__ X,
                                                   const float* __restrict__ Wa,
                                                   const float* __restrict__ Wb,
                                                   const float* __restrict__ Wc,
                                                   int na, int nab,
                                                   void* __restrict__ OUTv,
                                                   int Nd, int Kd, int act_n){
  __shared__ short As[128 * 40];
  __shared__ short Bs[128 * 40];
  const int tid  = threadIdx.x;
  const int lane = tid & 63;
  const int wv   = tid >> 6;
  const int wm   = wv >> 1, wn = wv & 1;
  const int bn0  = blockIdx.x * 128;
  const int bm0  = blockIdx.y * 128;
  const int l15  = lane & 15;
  const int quad = lane >> 4;

  f32x4 acc[4][4];
  #pragma unroll
  for (int mi = 0; mi < 4; ++mi)
    #pragma unroll
    for (int ni = 0; ni < 4; ++ni)
      #pragma unroll
      for (int rg = 0; rg < 4; ++rg) acc[mi][ni][rg] = 0.f;

  const int r    = tid >> 1;
  const int half = (tid & 1) * 16;

  int rr = bn0 + r;
  const float* wsrc = nullptr;
  if (rr < na)        wsrc = Wa + (size_t)rr * Kd;
  else if (rr < nab)  wsrc = Wb + (size_t)(rr - na) * Kd;
  else if (rr < Nd)   wsrc = Wc + (size_t)(rr - nab) * Kd;
  const bf16u* xsrc = X + (size_t)(bm0 + r) * Kd;

  for (int k0 = 0; k0 < Kd; k0 += 32){
    uint4 xa = *(const uint4*)(xsrc + k0 + half);
    uint4 xb = *(const uint4*)(xsrc + k0 + half + 8);
    uint4 w0 = make_uint4(0,0,0,0), w1 = w0, w2 = w0, w3 = w0;
    if (wsrc){
      w0 = *(const uint4*)(wsrc + k0 + half);
      w1 = *(const uint4*)(wsrc + k0 + half + 4);
      w2 = *(const uint4*)(wsrc + k0 + half + 8);
      w3 = *(const uint4*)(wsrc + k0 + half + 12);
    }
    union { unsigned short s[8]; uint4 v; } p0, p1;
    p0.s[0]=f2bfbits(w0.x); p0.s[1]=f2bfbits(w0.y); p0.s[2]=f2bfbits(w0.z); p0.s[3]=f2bfbits(w0.w);
    p0.s[4]=f2bfbits(w1.x); p0.s[5]=f2bfbits(w1.y); p0.s[6]=f2bfbits(w1.z); p0.s[7]=f2bfbits(w1.w);
    p1.s[0]=f2bfbits(w2.x); p1.s[1]=f2bfbits(w2.y); p1.s[2]=f2bfbits(w2.z); p1.s[3]=f2bfbits(w2.w);
    p1.s[4]=f2bfbits(w3.x); p1.s[5]=f2bfbits(w3.y); p1.s[6]=f2bfbits(w3.z); p1.s[7]=f2bfbits(w3.w);

    *(uint4*)&As[r * 40 + half]     = xa;
    *(uint4*)&As[r * 40 + half + 8] = xb;
    *(uint4*)&Bs[r * 40 + half]     = p0.v;
    *(uint4*)&Bs[r * 40 + half + 8] = p1.v;
    __syncthreads();

    short8 af[4], bfg[4];
    #pragma unroll
    for (int mi = 0; mi < 4; ++mi)
      af[mi] = *(const short8*)&As[(wm*64 + mi*16 + l15) * 40 + quad*8];
    #pragma unroll
    for (int ni = 0; ni < 4; ++ni)
      bfg[ni] = *(const short8*)&Bs[(wn*64 + ni*16 + l15) * 40 + quad*8];
    #pragma unroll
    for (int mi = 0; mi < 4; ++mi)
      #pragma unroll
      for (int ni = 0; ni < 4; ++ni)
        acc[mi][ni] = __builtin_amdgcn_mfma_f32_16x16x32_bf16(af[mi], bfg[ni], acc[mi][ni], 0, 0, 0);
    __syncthreads();
  }

  #pragma unroll
  for (int mi = 0; mi < 4; ++mi){
    #pragma unroll
    for (int ni = 0; ni < 4; ++ni){
      int col = bn0 + wn*64 + ni*16 + l15;
      if (col >= Nd) continue;
      #pragma unroll
      for (int rg = 0; rg < 4; ++rg){
        int row = bm0 + wm*64 + mi*16 + quad*4 + rg;
        float v = acc[mi][ni][rg];
        if (col < act_n) v = tanhf(v);
        if (OB) ((bf16u*)OUTv)[(size_t)row * Nd + col] = f2bf(v);
        else    ((float*)OUTv)[(size_t)row * Nd + col] = v;
      }
    }
  }
}

// ---------------------------------------------------------------------------
// MFMA NN GEMM: OUT[M, CC] = A[M, KD](bf16, row stride lda) @ B[KD, CC](f32).
// EP=0: plain bf16 store. EP=1: token-shift epilogue.
// ---------------------------------------------------------------------------
template<int KD, int EP>
__global__ __launch_bounds__(256) void k_gemm_nn(const bf16u* __restrict__ A, int lda,
                                                 const float* __restrict__ B,
                                                 bf16u* __restrict__ OUT,
                                                 const float* __restrict__ x,
                                                 const float* __restrict__ tma_g){
  __shared__ short As[128 * (KD + 8)];
  __shared__ short Bs[128 * (KD + 8)];
  const int tid  = threadIdx.x;
  const int lane = tid & 63;
  const int wv   = tid >> 6;
  const int wm   = wv >> 1, wn = wv & 1;
  const int bn0  = blockIdx.x * 128;
  const int bm0  = blockIdx.y * 128;
  const int l15  = lane & 15;
  const int quad = lane >> 4;

  for (int idx = tid; idx < 128 * (KD / 8); idx += 256){
    int r  = idx / (KD / 8);
    int kc = (idx % (KD / 8)) * 8;
    *(uint4*)&As[r * (KD + 8) + kc] =
        *(const uint4*)(A + (size_t)(bm0 + r) * lda + kc);
  }
  for (int idx = tid; idx < KD * 128; idx += 256){
    int k = idx >> 7, c = idx & 127;
    Bs[c * (KD + 8) + k] = (short)f2bf(B[(size_t)k * CC + bn0 + c]);
  }
  __syncthreads();

  f32x4 acc[4][4];
  #pragma unroll
  for (int mi = 0; mi < 4; ++mi)
    #pragma unroll
    for (int ni = 0; ni < 4; ++ni)
      #pragma unroll
      for (int rg = 0; rg < 4; ++rg) acc[mi][ni][rg] = 0.f;

  #pragma unroll
  for (int kk = 0; kk < KD; kk += 32){
    short8 af[4], bfg[4];
    #pragma unroll
    for (int mi = 0; mi < 4; ++mi)
      af[mi] = *(const short8*)&As[(wm*64 + mi*16 + l15) * (KD + 8) + kk + quad*8];
    #pragma unroll
    for (int ni = 0; ni < 4; ++ni)
      bfg[ni] = *(const short8*)&Bs[(wn*64 + ni*16 + l15) * (KD + 8) + kk + quad*8];
    #pragma unroll
    for (int mi = 0; mi < 4; ++mi)
      #pragma unroll
      for (int ni = 0; ni < 4; ++ni)
        acc[mi][ni] = __builtin_amdgcn_mfma_f32_16x16x32_bf16(af[mi], bfg[ni], acc[mi][ni], 0, 0, 0);
  }

  #pragma unroll
  for (int mi = 0; mi < 4; ++mi){
    #pragma unroll
    for (int ni = 0; ni < 4; ++ni){
      int col = bn0 + wn*64 + ni*16 + l15;
      float tm = (EP == 1) ? tma_g[col] : 0.f;
      #pragma unroll
      for (int rg = 0; rg < 4; ++rg){
        int row = bm0 + wm*64 + mi*16 + quad*4 + rg;
        float v = acc[mi][ni][rg];
        if (EP == 1){
          float xv = x[(size_t)row * CC + col];
          float xp = ((row & (TT - 1)) == 0) ? 0.f : x[(size_t)row * CC + col - CC];
          v = xv + (xp - xv) * (v + tm);
        }
        OUT[(size_t)row * CC + col] = f2bf(v);
      }
    }
  }
}

// ---------------------------------------------------------------------------
// Fused elementwise, tiled 4 tokens/block.
// ---------------------------------------------------------------------------
__global__ __launch_bounds__(256) void k_elem(bf16u* __restrict__ K0,
    const bf16u* __restrict__ P1, const bf16u* __restrict__ P2,
    const bf16u* __restrict__ W2A,
    const float* __restrict__ kw2, const float* __restrict__ aw2,
    const float* __restrict__ maw2, const float* __restrict__ mkw2,
    const float* __restrict__ td,  const float* __restrict__ taa,
    const float* __restrict__ tma, const float* __restrict__ tmk,
    bf16u* __restrict__ KKN, bf16u* __restrict__ Bb, bf16u* __restrict__ UX){
  int n0 = blockIdx.x * 4, tid = threadIdx.x;
  __shared__ float at_l[4][16], mat_l[4][16], kt_l[4][16], mkt_l[4][16];
  {
    int grp = tid >> 6, q = tid & 63, tt = q >> 4, j = q & 15;
    if (grp == 0)      at_l[tt][j]  = bf2f(P1[(size_t)(n0+tt)*96 + 64 + j]);
    else if (grp == 1) mat_l[tt][j] = bf2f(P1[(size_t)(n0+tt)*96 + 80 + j]);
    else if (grp == 2) kt_l[tt][j]  = bf2f(P2[(size_t)(n0+tt)*32 + j]);
    else               mkt_l[tt][j] = bf2f(P2[(size_t)(n0+tt)*32 + 16 + j]);
  }
  __syncthreads();
  int c = tid * 4;

  float kkk[4][4], aa[4][4], mam[4][4], mkm[4][4];
  #pragma unroll
  for (int tt = 0; tt < 4; ++tt)
    #pragma unroll
    for (int i = 0; i < 4; ++i){ kkk[tt][i]=0; aa[tt][i]=0; mam[tt][i]=0; mkm[tt][i]=0; }

  #pragma unroll 4
  for (int j = 0; j < 16; ++j){
    float wk[4], wa[4], wm[4], wq[4];
    ld4f(kw2  + (size_t)j*CC + c, wk);
    ld4f(aw2  + (size_t)j*CC + c, wa);
    ld4f(maw2 + (size_t)j*CC + c, wm);
    ld4f(mkw2 + (size_t)j*CC + c, wq);
    #pragma unroll
    for (int tt = 0; tt < 4; ++tt){
      float s1 = kt_l[tt][j], s2 = at_l[tt][j], s3 = mat_l[tt][j], s4 = mkt_l[tt][j];
      #pragma unroll
      for (int i = 0; i < 4; ++i){
        kkk[tt][i] += s1 * wk[i];
        aa[tt][i]  += s2 * wa[i];
        mam[tt][i] += s3 * wm[i];
        mkm[tt][i] += s4 * wq[i];
      }
    }
  }

  float td4[4], taa4[4], tma4[4], tmk4[4];
  ld4f(td + c, td4); ld4f(taa + c, taa4); ld4f(tma + c, tma4); ld4f(tmk + c, tmk4);

  for (int tt = 0; tt < 4; ++tt){
    size_t e = (size_t)(n0 + tt) * CC + c;
    float k0a[4]; ld4bf(K0 + e, k0a);
    float w2a[4]; ld4bf(W2A + e, w2a);

    float kkv[4];
    float ssq = 0.f;
    #pragma unroll
    for (int i = 0; i < 4; ++i){ kkv[i] = k0a[i] + kkk[tt][i]; ssq += kkv[i]*kkv[i]; }
    ssq = red16(ssq);
    float rinv = 1.f / fmaxf(sqrtf(ssq), 1e-12f);

    float kkn[4], outb[4], outkf[4], outu[4];
    #pragma unroll
    for (int i = 0; i < 4; ++i){
      float z  = td4[i] + w2a[i];
      float nz = -z;
      float sp = (nz > 15.f) ? nz : log1pf(expf(nz));
      float w  = -sp - 0.5f;               // <= -0.5
      float av  = sigm(taa4[i] + aa[tt][i]);
      float mav = sigm(tma4[i] + mam[tt][i]);
      float mkv = sigm(tmk4[i] + mkm[tt][i]);
      kkn[i]  = kkv[i] * rinv;
      outb[i] = -kkn[i] * av;
      outkf[i]= k0a[i] * (mav + av * (1.f - mav)) * expf(w * mkv);
      outu[i] = expf(w);                   // in (0, 0.61]
    }
    st4bf(KKN + e, kkn);
    st4bf(Bb  + e, outb);
    st4bf(K0  + e, outkf);
    st4bf(UX  + e, outu);
  }
}

// ---------------------------------------------------------------------------
// Recurrence v5: row-parallel, barrier/LDS-free, DPP reductions (no
// ds_bpermute on the serial chain), native exp, deferred-yp.
// ---------------------------------------------------------------------------
__global__ __launch_bounds__(256) void k_rec(const bf16u* __restrict__ Q,
                                             const bf16u* __restrict__ UX,
                                             const bf16u* __restrict__ KFt,
                                             const bf16u* __restrict__ Vt,
                                             const bf16u* __restrict__ Aa,
                                             const bf16u* __restrict__ Bv,
                                             bf16u* __restrict__ Y){
  const int blk = blockIdx.x;          // 0..255
  const int b   = blk >> 6;
  const int h   = (blk >> 2) & 15;
  const int rg  = blk & 3;
  const int tid = threadIdx.x;
  const int cg  = tid & 15;
  const int i   = rg * 16 + (tid >> 4);
  const int j0  = cg * 4;
  const size_t base0 = (size_t)(b * TT) * CC + h * HSS;

  float S0 = 0.f, S1 = 0.f, S2 = 0.f, S3 = 0.f;
  float ypA = 0.f, ypB = 0.f, ypC = 0.f, ypD = 0.f;

  ushort4 qA, kA, aA, bA, uA; unsigned short vA;
  ushort4 qB, kB, aB, bB, uB; unsigned short vB;
  ushort4 qC, kC, aC, bC, uC; unsigned short vC;
  ushort4 qD, kD, aD, bD, uD; unsigned short vD;

#define KREC_LOAD(SFX, T_) do{ \
    size_t bn_ = base0 + (size_t)(T_) * CC; \
    q##SFX = *(const ushort4*)(Q   + bn_ + j0); \
    k##SFX = *(const ushort4*)(KFt + bn_ + j0); \
    a##SFX = *(const ushort4*)(Aa  + bn_ + j0); \
    b##SFX = *(const ushort4*)(Bv  + bn_ + j0); \
    u##SFX = *(const ushort4*)(UX  + bn_ + j0); \
    v##SFX = Vt[bn_ + i]; \
  }while(0)

#define KREC_STEP(SFX) do{ \
    float a0 = bf2f(a##SFX.x), a1 = bf2f(a##SFX.y), a2 = bf2f(a##SFX.z), a3 = bf2f(a##SFX.w); \
    float w0 = __expf(-bf2f(u##SFX.x)), w1 = __expf(-bf2f(u##SFX.y)); \
    float w2 = __expf(-bf2f(u##SFX.z)), w3 = __expf(-bf2f(u##SFX.w)); \
    float k0 = bf2f(k##SFX.x), k1 = bf2f(k##SFX.y), k2 = bf2f(k##SFX.z), k3 = bf2f(k##SFX.w); \
    float b0 = bf2f(b##SFX.x), b1 = bf2f(b##SFX.y), b2 = bf2f(b##SFX.z), b3 = bf2f(b##SFX.w); \
    float q0 = bf2f(q##SFX.x), q1 = bf2f(q##SFX.y), q2 = bf2f(q##SFX.z), q3 = bf2f(q##SFX.w); \
    float vi = bf2f(v##SFX); \
    float sa = (S0 * a0 + S1 * a1) + (S2 * a2 + S3 * a3); \
    sa = red16(sa); \
    S0 = fmaf(S0, w0, fmaf(sa, b0, vi * k0)); \
    S1 = fmaf(S1, w1, fmaf(sa, b1, vi * k1)); \
    S2 = fmaf(S2, w2, fmaf(sa, b2, vi * k2)); \
    S3 = fmaf(S3, w3, fmaf(sa, b3, vi * k3)); \
    yp##SFX = (S0 * q0 + S1 * q1) + (S2 * q2 + S3 * q3); \
  }while(0)

#define KREC_FLUSH(SFX, T_) do{ \
    float yp_ = red16(yp##SFX); \
    if (cg == 0) Y[base0 + (size_t)(T_) * CC + i] = f2bf(yp_); \
  }while(0)

  KREC_LOAD(A, 0); KREC_LOAD(B, 1); KREC_LOAD(C, 2); KREC_LOAD(D, 3);
  for (int t = 0; t < TT; t += 4){
    KREC_STEP(A);
    if (t) KREC_FLUSH(D, t - 1);
    if (t + 4 < TT) KREC_LOAD(A, t + 4);
    KREC_STEP(B);
    KREC_FLUSH(A, t);
    if (t + 5 < TT) KREC_LOAD(B, t + 5);
    KREC_STEP(C);
    KREC_FLUSH(B, t + 1);
    if (t + 6 < TT) KREC_LOAD(C, t + 6);
    KREC_STEP(D);
    KREC_FLUSH(C, t + 2);
    if (t + 7 < TT) KREC_LOAD(D, t + 7);
  }
  KREC_FLUSH(D, TT - 1);
#undef KREC_LOAD
#undef KREC_STEP
#undef KREC_FLUSH
}

// ---------------------------------------------------------------------------
// Post: GroupNorm + bonus (r.k*faaaa)v + precomputed gate GV -> YG (bf16)
// ---------------------------------------------------------------------------
__global__ __launch_bounds__(256) void k_post(const bf16u* __restrict__ Y,
                                              const bf16u* __restrict__ R,
                                              const bf16u* __restrict__ KFt,
                                              const bf16u* __restrict__ Vt,
                                              const bf16u* __restrict__ GV,
                                              const float* __restrict__ lnw,
                                              const float* __restrict__ lnb,
                                              const float* __restrict__ faaaa,
                                              bf16u* __restrict__ YG){
  int n = blockIdx.x, tid = threadIdx.x;
  int c = tid * 4;
  size_t e = (size_t)n * CC + c;

  float ya[4]; ld4bf(Y + e, ya);
  float s = ya[0] + ya[1] + ya[2] + ya[3];
  s = red16(s);
  float mu = s * (1.f / 64.f);
  float d[4], vs = 0.f;
  #pragma unroll
  for (int i = 0; i < 4; ++i){ d[i] = ya[i] - mu; vs += d[i] * d[i]; }
  vs = red16(vs);
  float rstd = rsqrtf(vs * (1.f / 64.f) + EPSGN);

  float r4[4], k4[4], va[4], fa4[4];
  ld4bf(R + e, r4); ld4bf(KFt + e, k4); ld4bf(Vt + e, va);
  ld4f(faaaa + c, fa4);
  float rk = r4[0]*k4[0]*fa4[0] + r4[1]*k4[1]*fa4[1] + r4[2]*k4[2]*fa4[2] + r4[3]*k4[3]*fa4[3];
  rk = red16(rk);

  float lw4[4], lb4[4];
  ld4f(lnw + c, lw4); ld4f(lnb + c, lb4);
  float g[4]; ld4bf(GV + e, g);
  float o[4];
  #pragma unroll
  for (int i = 0; i < 4; ++i){
    float yn = d[i] * rstd * lw4[i] + lb4[i] + rk * va[i];
    o[i] = yn * g[i];
  }
  st4bf(YG + e, o);
}

// ---------------------------------------------------------------------------
extern "C" void kernel_launch(void* const* d_in, const int* in_sizes, int n_in,
                              void* d_out, int out_size, void* d_ws, size_t ws_size,
                              hipStream_t stream){
  (void)in_sizes; (void)n_in; (void)out_size; (void)ws_size;
  const float* x        = (const float*)d_in[0];
  const float* tmx      = (const float*)d_in[1];
  const float* tmaa     = (const float*)d_in[2];
  const float* maa_w1   = (const float*)d_in[3];
  const float* maa_w2   = (const float*)d_in[4];
  const float* decay_w1 = (const float*)d_in[5];
  const float* decay_w2 = (const float*)d_in[6];
  const float* aaa_w1   = (const float*)d_in[7];
  const float* aaa_w2   = (const float*)d_in[8];
  const float* kkk_w1   = (const float*)d_in[9];
  const float* kkk_w2   = (const float*)d_in[10];
  const float* gate_w1  = (const float*)d_in[11];
  const float* gate_w2  = (const float*)d_in[12];
  const float* ma_w1    = (const float*)d_in[13];
  const float* ma_w2    = (const float*)d_in[14];
  const float* mk_w1    = (const float*)d_in[15];
  const float* mk_w2    = (const float*)d_in[16];
  const float* t_decay  = (const float*)d_in[17];
  const float* t_faaaa  = (const float*)d_in[18];
  const float* t_aaaaa  = (const float*)d_in[19];
  const float* t_misc_a = (const float*)d_in[20];
  const float* t_misc_k = (const float*)d_in[21];
  const float* Wr       = (const float*)d_in[22];
  const float* Wk       = (const float*)d_in[23];
  const float* Wv       = (const float*)d_in[24];
  const float* Wo       = (const float*)d_in[25];
  const float* ln_w     = (const float*)d_in[26];
  const float* ln_b     = (const float*)d_in[27];

  // Slot map (8MiB bf16 each), 56 MiB + ~3 MiB smalls:
  // S0: MIX -> X0 -> KKN -> YG | S1: X1 -> Bb -> GV | S2: X2 -> UX
  // S3: X3 -> W2A -> Yb | S4: R | S5: K0 -> KF | S6: V
  bf16u* bw  = (bf16u*)d_ws;
  bf16u* MIX = bw + 0*SLOT;
  bf16u* X0  = bw + 0*SLOT;
  bf16u* KKN = bw + 0*SLOT;
  bf16u* YG  = bw + 0*SLOT;
  bf16u* X1  = bw + 1*SLOT;
  bf16u* Bb  = bw + 1*SLOT;
  bf16u* GV  = bw + 1*SLOT;
  bf16u* X2  = bw + 2*SLOT;
  bf16u* UX  = bw + 2*SLOT;
  bf16u* X3  = bw + 3*SLOT;
  bf16u* W2A = bw + 3*SLOT;
  bf16u* Yb  = bw + 3*SLOT;
  bf16u* R   = bw + 4*SLOT;
  bf16u* K0  = bw + 5*SLOT;   // becomes KF
  bf16u* V   = bw + 6*SLOT;
  char*  wsb = (char*)d_ws;
  bf16u* LO  = (bf16u*)(wsb + (56ull<<20));   // [N,128] bf16, 1 MiB
  bf16u* GT  = (bf16u*)(wsb + (57ull<<20));   // [N,128] bf16, 1 MiB
  bf16u* P1  = (bf16u*)(wsb + (58ull<<20));   // [N,96]  bf16 (dt|at|ma)
  bf16u* P2  = (bf16u*)(wsb + (58ull<<20) + (768ull<<10)); // [N,32] bf16

  // 1. mix
  k_prep<<<4096, 256, 0, stream>>>(x, tmx, MIX);
  // 2. lo = tanh(mix @ maa_w1^T) [N,128] bf16
  k_gemm_mfma<true><<<dim3(1,32),256,0,stream>>>(MIX, maa_w1, maa_w1, maa_w1,
                                                 128, 128, LO, 128, CC, 128);
  // 3. xm[g] = x + xx*(lo_g @ maa_w2_g + tmaa_g)   (NN GEMM + fused epilogue)
  bf16u* XMs[4] = {X0, X1, X2, X3};
  for (int g = 0; g < 4; ++g)
    k_gemm_nn<32,1><<<dim3(8,32),256,0,stream>>>(LO + g*32, 128,
                                                 maa_w2 + (size_t)g*32*CC,
                                                 XMs[g], x, tmaa + (size_t)g*CC);
  // 4. big projections (bf16 out)
  k_gemm_mfma<true><<<dim3(8,32),256,0,stream>>>(X0, Wr, Wr, Wr, CC, CC, R,  CC, CC, 0);
  k_gemm_mfma<true><<<dim3(8,32),256,0,stream>>>(X2, Wk, Wk, Wk, CC, CC, K0, CC, CC, 0);
  k_gemm_mfma<true><<<dim3(8,32),256,0,stream>>>(X3, Wv, Wv, Wv, CC, CC, V,  CC, CC, 0);
  // 5. first-stage LoRA projections (bf16 out)
  k_gemm_mfma<true><<<dim3(1,32),256,0,stream>>>(X0, gate_w1, gate_w1, gate_w1,
                                                 128, 128, GT, 128, CC, 128);
  k_gemm_mfma<true><<<dim3(1,32),256,0,stream>>>(X1, decay_w1, aaa_w1, ma_w1,
                                                 64, 80, P1, 96, CC, 64);
  k_gemm_mfma<true><<<dim3(1,32),256,0,stream>>>(X2, kkk_w1, mk_w1, mk_w1,
                                                 16, 32, P2, 32, CC, 16);
  // 6. decay second-stage projection: W2A = P1[:, :64] @ decay_w2  -> S3
  k_gemm_nn<64,0><<<dim3(8,32),256,0,stream>>>(P1, 96, decay_w2, W2A, nullptr, nullptr);
  // 7. fused elementwise (4 tokens/block)
  k_elem<<<1024, 256, 0, stream>>>(K0, P1, P2, W2A,
                                   kkk_w2, aaa_w2, ma_w2, mk_w2,
                                   t_decay, t_aaaaa, t_misc_a, t_misc_k,
                                   KKN, Bb, UX);
  // 8. delta-rule recurrence (DPP reductions)
  k_rec<<<256, 256, 0, stream>>>(R, UX, K0, V, KKN, Bb, Yb);
  // 9. gate second-stage: GV = GT @ gate_w2 -> S1 (Bb dead after k_rec)
  k_gemm_nn<128,0><<<dim3(8,32),256,0,stream>>>(GT, 128, gate_w2, GV, nullptr, nullptr);
  // 10. groupnorm + bonus + gate
  k_post<<<4096, 256, 0, stream>>>(Yb, R, K0, V, GV, ln_w, ln_b, t_faaaa, YG);
  // 11. out = yg @ Wo^T -> f32
  k_gemm_mfma<false><<<dim3(8,32),256,0,stream>>>(YG, Wo, Wo, Wo, CC, CC, d_out, CC, CC, 0);
}